// Round 7
// baseline (1851.996 us; speedup 1.0000x reference)
//
#include <hip/hip_runtime.h>
#include <stdint.h>

typedef unsigned short u16;
typedef float f32x4 __attribute__((ext_vector_type(4)));
typedef short short8 __attribute__((ext_vector_type(8)));  // 8 bf16 in 4 VGPRs

__device__ __forceinline__ u16 f2bf(float f) {
  union { float f; uint32_t u; } v; v.f = f;
  return (u16)((v.u + 0x7FFFu + ((v.u >> 16) & 1u)) >> 16);
}
__device__ __forceinline__ uint32_t pack2(u16 lo, u16 hi) {
  return (uint32_t)lo | ((uint32_t)hi << 16);
}

#define MFMA16(a, b, c) __builtin_amdgcn_mfma_f32_16x16x32_bf16((a), (b), (c), 0, 0, 0)

// ---------------------------------------------------------------------------
// Weight fp32 -> bf16 conversion (Wv, Wo)
// ---------------------------------------------------------------------------
__global__ void conv_w(const float* __restrict__ src, u16* __restrict__ dst, int n4) {
  int i = blockIdx.x * blockDim.x + threadIdx.x;
  if (i >= n4) return;
  float4 v = ((const float4*)src)[i];
  uint2 p;
  p.x = pack2(f2bf(v.x), f2bf(v.y));
  p.y = pack2(f2bf(v.z), f2bf(v.w));
  ((uint2*)dst)[i] = p;
}

// ---------------------------------------------------------------------------
// Q/K projection (fp32 VALU, ~2 GFLOP): Q scaled by log2e. Layout [B][N][32].
// ---------------------------------------------------------------------------
__global__ __launch_bounds__(256) void qk_proj(
    const float* __restrict__ x, const float* __restrict__ Wq,
    const float* __restrict__ bq, const float* __restrict__ Wk,
    const float* __restrict__ bk, u16* __restrict__ Qb, u16* __restrict__ Kb) {
  const int b = blockIdx.y, nb = blockIdx.x * 64;
  const int t = threadIdx.x;
  __shared__ __align__(16) float xs[64][64];
  __shared__ __align__(16) float ws[64][72];

  const int r0 = (t >> 4) * 4, n0 = (t & 15) * 4;
  float acc[4][4];
#pragma unroll
  for (int i = 0; i < 4; ++i)
#pragma unroll
    for (int j = 0; j < 4; ++j) acc[i][j] = 0.0f;

  for (int c0 = 0; c0 < 512; c0 += 64) {
#pragma unroll
    for (int p = 0; p < 4; ++p) {
      int idx = t + p * 256;
      int c = idx >> 4, nn = (idx & 15) * 4;
      *(float4*)&xs[c][nn] =
          *(const float4*)&x[((size_t)(b * 512 + c0 + c)) * 4096 + nb + nn];
    }
#pragma unroll
    for (int p = 0; p < 4; ++p) {
      int idx = t + p * 256;
      int r = idx >> 4, cc = (idx & 15) * 4;
      const float* Wrow = (r < 32) ? (Wq + (size_t)r * 512) : (Wk + (size_t)(r - 32) * 512);
      *(float4*)&ws[r][cc] = *(const float4*)&Wrow[c0 + cc];
    }
    __syncthreads();
    for (int c = 0; c < 64; c += 4) {
      float4 xa0 = *(const float4*)&xs[c + 0][n0];
      float4 xa1 = *(const float4*)&xs[c + 1][n0];
      float4 xa2 = *(const float4*)&xs[c + 2][n0];
      float4 xa3 = *(const float4*)&xs[c + 3][n0];
#pragma unroll
      for (int i = 0; i < 4; ++i) {
        float4 wa = *(const float4*)&ws[r0 + i][c];
        acc[i][0] += wa.x * xa0.x + wa.y * xa1.x + wa.z * xa2.x + wa.w * xa3.x;
        acc[i][1] += wa.x * xa0.y + wa.y * xa1.y + wa.z * xa2.y + wa.w * xa3.y;
        acc[i][2] += wa.x * xa0.z + wa.y * xa1.z + wa.z * xa2.z + wa.w * xa3.z;
        acc[i][3] += wa.x * xa0.w + wa.y * xa1.w + wa.z * xa2.w + wa.w * xa3.w;
      }
    }
    __syncthreads();
  }

  const float LOG2E = 1.4426950408889634f;
#pragma unroll
  for (int i = 0; i < 4; ++i) {
    int r = r0 + i;
#pragma unroll
    for (int j = 0; j < 4; ++j) {
      int n = nb + n0 + j;
      if (r < 32) {
        Qb[((size_t)(b * 4096 + n)) * 32 + r] = f2bf((acc[i][j] + bq[r]) * LOG2E);
      } else {
        Kb[((size_t)(b * 4096 + n)) * 32 + (r - 32)] = f2bf(acc[i][j] + bk[r - 32]);
      }
    }
  }
}

// ---------------------------------------------------------------------------
// V projection: V[b][o][n] = Wv x + bv (bf16, [B][C][N]); MFMA GEMM with
// x-tile transposed into XOR-swizzled LDS.
// grid = (n-tiles=64, o-tiles=8, b=8); block covers 64o x 64n.
// ---------------------------------------------------------------------------
__global__ __launch_bounds__(256) void v_proj(
    const float* __restrict__ x, const u16* __restrict__ Wvb,
    const float* __restrict__ bv, u16* __restrict__ Vb) {
  const int b = blockIdx.z, ob = blockIdx.y * 64, nb = blockIdx.x * 64;
  const int t = threadIdx.x, w = t >> 6, lane = t & 63, g = lane >> 4, l15 = lane & 15;
  const int wo = (w >> 1) * 32, wn = (w & 1) * 32;
  __shared__ __align__(16) u16 xT[64][64];  // row = n (128B rows), swizzled

  f32x4 zero4 = {0.f, 0.f, 0.f, 0.f};
  f32x4 acc[2][2];
  acc[0][0] = zero4; acc[0][1] = zero4; acc[1][0] = zero4; acc[1][1] = zero4;

  const int cq4 = (t >> 4) * 4, n4 = (t & 15) * 4;

  for (int c0 = 0; c0 < 512; c0 += 64) {
    float4 q0 = *(const float4*)&x[((size_t)(b * 512 + c0 + cq4 + 0)) * 4096 + nb + n4];
    float4 q1 = *(const float4*)&x[((size_t)(b * 512 + c0 + cq4 + 1)) * 4096 + nb + n4];
    float4 q2 = *(const float4*)&x[((size_t)(b * 512 + c0 + cq4 + 2)) * 4096 + nb + n4];
    float4 q3 = *(const float4*)&x[((size_t)(b * 512 + c0 + cq4 + 3)) * 4096 + nb + n4];
    float rr[4][4];
    rr[0][0] = q0.x; rr[0][1] = q0.y; rr[0][2] = q0.z; rr[0][3] = q0.w;
    rr[1][0] = q1.x; rr[1][1] = q1.y; rr[1][2] = q1.z; rr[1][3] = q1.w;
    rr[2][0] = q2.x; rr[2][1] = q2.y; rr[2][2] = q2.z; rr[2][3] = q2.w;
    rr[3][0] = q3.x; rr[3][1] = q3.y; rr[3][2] = q3.z; rr[3][3] = q3.w;
#pragma unroll
    for (int k = 0; k < 4; ++k) {
      int row = n4 + k;
      uint2 pk;
      pk.x = pack2(f2bf(rr[0][k]), f2bf(rr[1][k]));
      pk.y = pack2(f2bf(rr[2][k]), f2bf(rr[3][k]));
      int byte = row * 128 + ((cq4 * 2) ^ ((row & 7) << 4));
      *(uint2*)((char*)&xT[0][0] + byte) = pk;
    }
    __syncthreads();

    short8 af[2][2], bb[2][2];
#pragma unroll
    for (int ot = 0; ot < 2; ++ot)
#pragma unroll
      for (int ks = 0; ks < 2; ++ks)
        af[ot][ks] = *(const short8*)&Wvb[(size_t)(ob + wo + ot * 16 + l15) * 512 + c0 + ks * 32 + g * 8];
#pragma unroll
    for (int nt = 0; nt < 2; ++nt)
#pragma unroll
      for (int ks = 0; ks < 2; ++ks) {
        int row = wn + nt * 16 + l15;
        int byte = row * 128 + (((ks * 64) + (g * 16)) ^ ((row & 7) << 4));
        bb[nt][ks] = *(const short8*)((const char*)&xT[0][0] + byte);
      }
#pragma unroll
    for (int ks = 0; ks < 2; ++ks)
#pragma unroll
      for (int ot = 0; ot < 2; ++ot)
#pragma unroll
        for (int nt = 0; nt < 2; ++nt)
          acc[ot][nt] = MFMA16(af[ot][ks], bb[nt][ks], acc[ot][nt]);
    __syncthreads();
  }

#pragma unroll
  for (int ot = 0; ot < 2; ++ot)
#pragma unroll
    for (int nt = 0; nt < 2; ++nt)
#pragma unroll
      for (int r = 0; r < 4; ++r) {
        int o = ob + wo + ot * 16 + g * 4 + r;
        int n = nb + wn + nt * 16 + l15;
        Vb[((size_t)(b * 512 + o)) * 4096 + n] = f2bf(acc[ot][nt][r] + bv[o]);
      }
}

// ---------------------------------------------------------------------------
// Flash attention v2 (correctness-first):
//   block = (b, 64 q-rows), 4 independent waves; wave owns 16 q-rows x ALL keys.
//   Fixed-max softmax: p = 2^s directly (range-safe: |s|<~75).
//   No barriers, no cross-wave exchange, wave-private padded LDS for P.
// ---------------------------------------------------------------------------
__global__ __launch_bounds__(256) void attn2(
    const u16* __restrict__ Qb, const u16* __restrict__ Kb,
    const u16* __restrict__ Vb, u16* __restrict__ AOb) {
  const int bid = blockIdx.x;
  const int b = bid & 7;                 // XCD-pinned batch (V[b] fits one L2)
  const int qb = (bid >> 3) * 64;
  const int t = threadIdx.x;
  const int w = t >> 6, lane = t & 63, g = lane >> 4, l15 = lane & 15;
  const int qw = qb + w * 16;            // this wave's 16 q-rows

  __shared__ __align__(16) u16 P[4][16][80];  // wave-private, padded rows (160B)

  f32x4 zero4 = {0.f, 0.f, 0.f, 0.f};

  // Q fragment: A rows = l15 -> q-row qw+l15, k = g*8+j (channel)
  short8 qf = *(const short8*)&Qb[((size_t)(b * 4096 + qw + l15)) * 32 + g * 8];

  f32x4 acc[32];                          // 32 channel-tiles x 4 acc rows
#pragma unroll
  for (int ct = 0; ct < 32; ++ct) acc[ct] = zero4;
  float l_[4] = {0.f, 0.f, 0.f, 0.f};

  const size_t kb0 = (size_t)b * 4096;

  for (int kv = 0; kv < 4096; kv += 64) {
    // S for all 64 keys of this tile (4 slices of 16)
    f32x4 s[4];
#pragma unroll
    for (int ks = 0; ks < 4; ++ks) {
      short8 kf = *(const short8*)&Kb[(kb0 + kv + ks * 16 + l15) * 32 + g * 8];
      s[ks] = MFMA16(qf, kf, zero4);      // D: row=g*4+r (q-local), col=l15 (key)
    }
    // p = 2^s ; accumulate row sums; write P transposed via wave-private LDS
#pragma unroll
    for (int r = 0; r < 4; ++r) {
      float rowsum = 0.f;
#pragma unroll
      for (int ks = 0; ks < 4; ++ks) {
        float p = exp2f(s[ks][r]);
        rowsum += p;
        P[w][g * 4 + r][ks * 16 + l15] = f2bf(p);
      }
      rowsum += __shfl_xor(rowsum, 1);
      rowsum += __shfl_xor(rowsum, 2);
      rowsum += __shfl_xor(rowsum, 4);
      rowsum += __shfl_xor(rowsum, 8);
      l_[r] += rowsum;                    // row g*4+r: sum over all 64 keys
    }
    // PV: P as A-frag (row=l15, k=g*8+j over keys), V as B-frag
    short8 pf0 = *(const short8*)&P[w][l15][g * 8];
    short8 pf1 = *(const short8*)&P[w][l15][32 + g * 8];
#pragma unroll
    for (int ct = 0; ct < 32; ++ct) {
      const u16* vbase = &Vb[((size_t)(b * 512 + ct * 16 + l15)) * 4096 + kv];
      short8 vf0 = *(const short8*)&vbase[g * 8];
      short8 vf1 = *(const short8*)&vbase[32 + g * 8];
      acc[ct] = MFMA16(pf0, vf0, acc[ct]);
      acc[ct] = MFMA16(pf1, vf1, acc[ct]);
    }
  }

  // epilogue: normalize, store AO [B][N][C]
  float inv[4];
#pragma unroll
  for (int r = 0; r < 4; ++r) inv[r] = 1.0f / l_[r];
#pragma unroll
  for (int ct = 0; ct < 32; ++ct)
#pragma unroll
    for (int r = 0; r < 4; ++r) {
      int qrow = qw + g * 4 + r;
      int c = ct * 16 + l15;
      AOb[((size_t)(b * 4096 + qrow)) * 512 + c] = f2bf(acc[ct][r] * inv[r]);
    }
}

// ---------------------------------------------------------------------------
// Output projection + residual: out = gamma*(Wo AO + bo) + x  -> FP32 d_out
// grid = (n-tiles=64, o-tiles=8, b=8); block covers 64o x 64n.
// ---------------------------------------------------------------------------
__global__ __launch_bounds__(256) void wo_out(
    const u16* __restrict__ AOb, const u16* __restrict__ Wob,
    const float* __restrict__ bo, const float* __restrict__ gamma,
    const float* __restrict__ x, float* __restrict__ out) {
  const int b = blockIdx.z, ob = blockIdx.y * 64, nb = blockIdx.x * 64;
  const int t = threadIdx.x, w = t >> 6, lane = t & 63, g = lane >> 4, l15 = lane & 15;
  const int wo = (w >> 1) * 32, wn = (w & 1) * 32;

  f32x4 zero4 = {0.f, 0.f, 0.f, 0.f};
  f32x4 acc[2][2];
  acc[0][0] = zero4; acc[0][1] = zero4; acc[1][0] = zero4; acc[1][1] = zero4;

  for (int c0 = 0; c0 < 512; c0 += 64) {
    short8 af[2][2], bb[2][2];
#pragma unroll
    for (int ot = 0; ot < 2; ++ot)
#pragma unroll
      for (int ks = 0; ks < 2; ++ks)
        af[ot][ks] = *(const short8*)&Wob[(size_t)(ob + wo + ot * 16 + l15) * 512 + c0 + ks * 32 + g * 8];
#pragma unroll
    for (int nt = 0; nt < 2; ++nt)
#pragma unroll
      for (int ks = 0; ks < 2; ++ks)
        bb[nt][ks] = *(const short8*)&AOb[((size_t)(b * 4096 + nb + wn + nt * 16 + l15)) * 512 + c0 + ks * 32 + g * 8];
#pragma unroll
    for (int ks = 0; ks < 2; ++ks)
#pragma unroll
      for (int ot = 0; ot < 2; ++ot)
#pragma unroll
        for (int nt = 0; nt < 2; ++nt)
          acc[ot][nt] = MFMA16(af[ot][ks], bb[nt][ks], acc[ot][nt]);
  }

  float gm = gamma[0];
#pragma unroll
  for (int ot = 0; ot < 2; ++ot)
#pragma unroll
    for (int nt = 0; nt < 2; ++nt)
#pragma unroll
      for (int r = 0; r < 4; ++r) {
        int o = ob + wo + ot * 16 + g * 4 + r;
        int n = nb + wn + nt * 16 + l15;
        size_t idx = ((size_t)(b * 512 + o)) * 4096 + n;
        out[idx] = gm * (acc[ot][nt][r] + bo[o]) + x[idx];
      }
}

// ---------------------------------------------------------------------------
// Workspace map (total 38.8 MB):
//   AOb  ws + 0          (32 MB)   [B][N][C]
//   Qb   ws + 33554432   ( 2 MB)   [B][N][32]
//   Kb   ws + 35651584   ( 2 MB)   [B][N][32]
//   Wvb  ws + 37748736   (0.5 MB)
//   Wob  ws + 38273024   (0.5 MB)
//   Vb   = d_out scratch (32 MB inside the 64 MB fp32 d_out); V fully consumed
//         by attn2 before wo_out overwrites every d_out element.
// ---------------------------------------------------------------------------
extern "C" void kernel_launch(void* const* d_in, const int* in_sizes, int n_in,
                              void* d_out, int out_size, void* d_ws, size_t ws_size,
                              hipStream_t stream) {
  (void)in_sizes; (void)n_in; (void)out_size; (void)ws_size;
  const float* x     = (const float*)d_in[0];
  const float* Wq    = (const float*)d_in[1];
  const float* bq    = (const float*)d_in[2];
  const float* Wk    = (const float*)d_in[3];
  const float* bk    = (const float*)d_in[4];
  const float* Wv    = (const float*)d_in[5];
  const float* bv    = (const float*)d_in[6];
  const float* Wo    = (const float*)d_in[7];
  const float* bo    = (const float*)d_in[8];
  const float* gamma = (const float*)d_in[9];

  char* wsb = (char*)d_ws;
  u16* AOb = (u16*)(wsb + 0);
  u16* Qb  = (u16*)(wsb + (size_t)33554432);
  u16* Kb  = (u16*)(wsb + (size_t)35651584);
  u16* Wvb = (u16*)(wsb + (size_t)37748736);
  u16* Wob = (u16*)(wsb + (size_t)38273024);
  u16* Vb  = (u16*)d_out;  // scratch inside fp32 d_out; rewritten by wo_out

  conv_w<<<256, 256, 0, stream>>>(Wv, Wvb, 65536);
  conv_w<<<256, 256, 0, stream>>>(Wo, Wob, 65536);
  qk_proj<<<dim3(64, 8), 256, 0, stream>>>(x, Wq, bq, Wk, bk, Qb, Kb);
  v_proj<<<dim3(64, 8, 8), 256, 0, stream>>>(x, Wvb, bv, Vb);
  attn2<<<512, 256, 0, stream>>>(Qb, Kb, Vb, AOb);
  wo_out<<<dim3(64, 8, 8), 256, 0, stream>>>(AOb, Wob, bo, gamma, x, (float*)d_out);
}

// Round 8
// 725.023 us; speedup vs baseline: 2.5544x; 2.5544x over previous
//
#include <hip/hip_runtime.h>
#include <stdint.h>

typedef unsigned short u16;
typedef float f32x4 __attribute__((ext_vector_type(4)));
typedef short short8 __attribute__((ext_vector_type(8)));  // 8 bf16 in 4 VGPRs

__device__ __forceinline__ u16 f2bf(float f) {
  union { float f; uint32_t u; } v; v.f = f;
  return (u16)((v.u + 0x7FFFu + ((v.u >> 16) & 1u)) >> 16);
}
__device__ __forceinline__ uint32_t pack2(u16 lo, u16 hi) {
  return (uint32_t)lo | ((uint32_t)hi << 16);
}

#define MFMA16(a, b, c) __builtin_amdgcn_mfma_f32_16x16x32_bf16((a), (b), (c), 0, 0, 0)

// ---------------------------------------------------------------------------
// Weight fp32 -> bf16 conversion (Wv, Wo)
// ---------------------------------------------------------------------------
__global__ void conv_w(const float* __restrict__ src, u16* __restrict__ dst, int n4) {
  int i = blockIdx.x * blockDim.x + threadIdx.x;
  if (i >= n4) return;
  float4 v = ((const float4*)src)[i];
  uint2 p;
  p.x = pack2(f2bf(v.x), f2bf(v.y));
  p.y = pack2(f2bf(v.z), f2bf(v.w));
  ((uint2*)dst)[i] = p;
}

// ---------------------------------------------------------------------------
// Q/K projection (fp32 VALU): Q scaled by log2e. Layout [B][N][32].
// ---------------------------------------------------------------------------
__global__ __launch_bounds__(256) void qk_proj(
    const float* __restrict__ x, const float* __restrict__ Wq,
    const float* __restrict__ bq, const float* __restrict__ Wk,
    const float* __restrict__ bk, u16* __restrict__ Qb, u16* __restrict__ Kb) {
  const int b = blockIdx.y, nb = blockIdx.x * 64;
  const int t = threadIdx.x;
  __shared__ __align__(16) float xs[64][64];
  __shared__ __align__(16) float ws[64][72];

  const int r0 = (t >> 4) * 4, n0 = (t & 15) * 4;
  float acc[4][4];
#pragma unroll
  for (int i = 0; i < 4; ++i)
#pragma unroll
    for (int j = 0; j < 4; ++j) acc[i][j] = 0.0f;

  for (int c0 = 0; c0 < 512; c0 += 64) {
#pragma unroll
    for (int p = 0; p < 4; ++p) {
      int idx = t + p * 256;
      int c = idx >> 4, nn = (idx & 15) * 4;
      *(float4*)&xs[c][nn] =
          *(const float4*)&x[((size_t)(b * 512 + c0 + c)) * 4096 + nb + nn];
    }
#pragma unroll
    for (int p = 0; p < 4; ++p) {
      int idx = t + p * 256;
      int r = idx >> 4, cc = (idx & 15) * 4;
      const float* Wrow = (r < 32) ? (Wq + (size_t)r * 512) : (Wk + (size_t)(r - 32) * 512);
      *(float4*)&ws[r][cc] = *(const float4*)&Wrow[c0 + cc];
    }
    __syncthreads();
    for (int c = 0; c < 64; c += 4) {
      float4 xa0 = *(const float4*)&xs[c + 0][n0];
      float4 xa1 = *(const float4*)&xs[c + 1][n0];
      float4 xa2 = *(const float4*)&xs[c + 2][n0];
      float4 xa3 = *(const float4*)&xs[c + 3][n0];
#pragma unroll
      for (int i = 0; i < 4; ++i) {
        float4 wa = *(const float4*)&ws[r0 + i][c];
        acc[i][0] += wa.x * xa0.x + wa.y * xa1.x + wa.z * xa2.x + wa.w * xa3.x;
        acc[i][1] += wa.x * xa0.y + wa.y * xa1.y + wa.z * xa2.y + wa.w * xa3.y;
        acc[i][2] += wa.x * xa0.z + wa.y * xa1.z + wa.z * xa2.z + wa.w * xa3.z;
        acc[i][3] += wa.x * xa0.w + wa.y * xa1.w + wa.z * xa2.w + wa.w * xa3.w;
      }
    }
    __syncthreads();
  }

  const float LOG2E = 1.4426950408889634f;
#pragma unroll
  for (int i = 0; i < 4; ++i) {
    int r = r0 + i;
#pragma unroll
    for (int j = 0; j < 4; ++j) {
      int n = nb + n0 + j;
      if (r < 32) {
        Qb[((size_t)(b * 4096 + n)) * 32 + r] = f2bf((acc[i][j] + bq[r]) * LOG2E);
      } else {
        Kb[((size_t)(b * 4096 + n)) * 32 + (r - 32)] = f2bf(acc[i][j] + bk[r - 32]);
      }
    }
  }
}

// ---------------------------------------------------------------------------
// V projection: V2 swizzled-tile layout for attn3 LDS staging.
//   V2 u16 index: b*2097152 + (n>>6)*32768 + c*64 + (((kk*2)^((c&7)<<4))>>1),
//   kk = n&63. grid = (n-tiles=64, b=8); block covers ALL 512 o (og loop).
// ---------------------------------------------------------------------------
__global__ __launch_bounds__(256) void v_proj(
    const float* __restrict__ x, const u16* __restrict__ Wvb,
    const float* __restrict__ bv, u16* __restrict__ V2) {
  const int b = blockIdx.y, nb = blockIdx.x * 64;
  const int t = threadIdx.x, w = t >> 6, lane = t & 63, g = lane >> 4, l15 = lane & 15;
  const int wo = (w >> 1) * 32, wn = (w & 1) * 32;
  __shared__ __align__(16) u16 xT[64][64];  // row = n (128B rows), swizzled

  f32x4 zero4 = {0.f, 0.f, 0.f, 0.f};
  f32x4 acc[8][2][2];
#pragma unroll
  for (int og = 0; og < 8; ++og)
#pragma unroll
    for (int ot = 0; ot < 2; ++ot)
#pragma unroll
      for (int nt = 0; nt < 2; ++nt) acc[og][ot][nt] = zero4;

  const int cq4 = (t >> 4) * 4, n4 = (t & 15) * 4;

  for (int c0 = 0; c0 < 512; c0 += 64) {
    float4 q0 = *(const float4*)&x[((size_t)(b * 512 + c0 + cq4 + 0)) * 4096 + nb + n4];
    float4 q1 = *(const float4*)&x[((size_t)(b * 512 + c0 + cq4 + 1)) * 4096 + nb + n4];
    float4 q2 = *(const float4*)&x[((size_t)(b * 512 + c0 + cq4 + 2)) * 4096 + nb + n4];
    float4 q3 = *(const float4*)&x[((size_t)(b * 512 + c0 + cq4 + 3)) * 4096 + nb + n4];
    float rr[4][4];
    rr[0][0] = q0.x; rr[0][1] = q0.y; rr[0][2] = q0.z; rr[0][3] = q0.w;
    rr[1][0] = q1.x; rr[1][1] = q1.y; rr[1][2] = q1.z; rr[1][3] = q1.w;
    rr[2][0] = q2.x; rr[2][1] = q2.y; rr[2][2] = q2.z; rr[2][3] = q2.w;
    rr[3][0] = q3.x; rr[3][1] = q3.y; rr[3][2] = q3.z; rr[3][3] = q3.w;
#pragma unroll
    for (int k = 0; k < 4; ++k) {
      int row = n4 + k;
      uint2 pk;
      pk.x = pack2(f2bf(rr[0][k]), f2bf(rr[1][k]));
      pk.y = pack2(f2bf(rr[2][k]), f2bf(rr[3][k]));
      int byte = row * 128 + ((cq4 * 2) ^ ((row & 7) << 4));
      *(uint2*)((char*)&xT[0][0] + byte) = pk;
    }
    __syncthreads();

    short8 bb[2][2];
#pragma unroll
    for (int nt = 0; nt < 2; ++nt)
#pragma unroll
      for (int ks = 0; ks < 2; ++ks) {
        int row = wn + nt * 16 + l15;
        int byte = row * 128 + (((ks * 64) + (g * 16)) ^ ((row & 7) << 4));
        bb[nt][ks] = *(const short8*)((const char*)&xT[0][0] + byte);
      }
#pragma unroll
    for (int og = 0; og < 8; ++og) {
      short8 af[2][2];
#pragma unroll
      for (int ot = 0; ot < 2; ++ot)
#pragma unroll
        for (int ks = 0; ks < 2; ++ks)
          af[ot][ks] = *(const short8*)&Wvb[(size_t)(og * 64 + wo + ot * 16 + l15) * 512 + c0 + ks * 32 + g * 8];
#pragma unroll
      for (int ks = 0; ks < 2; ++ks)
#pragma unroll
        for (int ot = 0; ot < 2; ++ot)
#pragma unroll
          for (int nt = 0; nt < 2; ++nt)
            acc[og][ot][nt] = MFMA16(af[ot][ks], bb[nt][ks], acc[og][ot][nt]);
    }
    __syncthreads();
  }

  const size_t tbase = (size_t)b * 2097152 + (size_t)(nb >> 6) * 32768;
#pragma unroll
  for (int og = 0; og < 8; ++og)
#pragma unroll
    for (int ot = 0; ot < 2; ++ot)
#pragma unroll
      for (int nt = 0; nt < 2; ++nt)
#pragma unroll
        for (int r = 0; r < 4; ++r) {
          int o = og * 64 + wo + ot * 16 + g * 4 + r;
          int kk = wn + nt * 16 + l15;
          int swz = ((kk * 2) ^ ((o & 7) << 4)) >> 1;
          V2[tbase + o * 64 + swz] = f2bf(acc[og][ot][nt][r] + bv[o]);
        }
}

// ---------------------------------------------------------------------------
// Flash attention v3: block = 128 q-rows x 512 ch, 8 waves (32q x 256ch each).
// grid = 256 (1 block/CU), batch = bid&7 (XCD-pinned). V tile (64 keys, all
// 512 ch, 64KB) staged once per block into LDS (swizzled), shared by 8 waves.
// Async staging: global->reg before S/softmax, ds_write after PV barrier.
// Softmax fixed-max exp2 domain (verified round 7).
// ---------------------------------------------------------------------------
__global__ __launch_bounds__(512, 2) void attn3(
    const u16* __restrict__ Qb, const u16* __restrict__ Kb,
    const u16* __restrict__ V2, u16* __restrict__ AOb) {
  const int bid = blockIdx.x;
  const int b = bid & 7;
  const int qblk = (bid >> 3) * 128;
  const int t = threadIdx.x;
  const int w = t >> 6, lane = t & 63, g = lane >> 4, l15 = lane & 15;
  const int qbase = qblk + (w >> 1) * 32;   // 4 q-groups of 32 rows
  const int chb = (w & 1) * 256;            // 2 channel halves

  __shared__ __align__(16) u16 Vlds[32768];      // [512 ch][64 keys] swizzled
  __shared__ __align__(16) u16 Plds[8][32][88];  // wave-private P, 176B rows

  f32x4 zero4 = {0.f, 0.f, 0.f, 0.f};

  short8 qf[2];
#pragma unroll
  for (int qt = 0; qt < 2; ++qt)
    qf[qt] = *(const short8*)&Qb[((size_t)(b * 4096 + qbase + qt * 16 + l15)) * 32 + g * 8];

  f32x4 acc[2][16];
#pragma unroll
  for (int qt = 0; qt < 2; ++qt)
#pragma unroll
    for (int ct = 0; ct < 16; ++ct) acc[qt][ct] = zero4;
  float l_[2][4] = {{0.f, 0.f, 0.f, 0.f}, {0.f, 0.f, 0.f, 0.f}};

  const u16* VB = V2 + (size_t)b * 2097152;
  const size_t kb0 = (size_t)b * 4096;

  // prologue: stage V tile 0
#pragma unroll
  for (int i = 0; i < 8; ++i) {
    uint4 v = *(const uint4*)&VB[(i * 512 + t) * 8];
    *(uint4*)&Vlds[(i * 512 + t) * 8] = v;
  }
  __syncthreads();

  for (int kv = 0; kv < 4096; kv += 64) {
    const bool more = (kv + 64) < 4096;
    uint4 stg[8];
    if (more) {
      const u16* Vt = VB + (size_t)((kv >> 6) + 1) * 32768;
#pragma unroll
      for (int i = 0; i < 8; ++i) stg[i] = *(const uint4*)&Vt[(i * 512 + t) * 8];
    }

    // S: 32 q-rows x 64 keys (4 slices)
    f32x4 s[2][4];
#pragma unroll
    for (int ks = 0; ks < 4; ++ks) {
      short8 kf = *(const short8*)&Kb[(kb0 + kv + ks * 16 + l15) * 32 + g * 8];
      s[0][ks] = MFMA16(qf[0], kf, zero4);
      s[1][ks] = MFMA16(qf[1], kf, zero4);
    }

    // p = 2^s, row sums, P to wave-private LDS (transpose)
#pragma unroll
    for (int qt = 0; qt < 2; ++qt)
#pragma unroll
      for (int r = 0; r < 4; ++r) {
        float rs = 0.f;
#pragma unroll
        for (int ks = 0; ks < 4; ++ks) {
          float p = exp2f(s[qt][ks][r]);
          rs += p;
          Plds[w][qt * 16 + g * 4 + r][ks * 16 + l15] = f2bf(p);
        }
        rs += __shfl_xor(rs, 1);
        rs += __shfl_xor(rs, 2);
        rs += __shfl_xor(rs, 4);
        rs += __shfl_xor(rs, 8);
        l_[qt][r] += rs;
      }

    // PV: V from swizzled LDS (shared), P from wave-private LDS
    short8 pf[2][2];
#pragma unroll
    for (int qt = 0; qt < 2; ++qt)
#pragma unroll
      for (int k2 = 0; k2 < 2; ++k2)
        pf[qt][k2] = *(const short8*)&Plds[w][qt * 16 + l15][k2 * 32 + g * 8];
#pragma unroll
    for (int ct = 0; ct < 16; ++ct) {
      int c = chb + ct * 16 + l15;
      int sw = (c & 7) << 4;
      const char* vrow = (const char*)&Vlds[0] + c * 128;
      short8 vf0 = *(const short8*)(vrow + ((g * 16) ^ sw));
      short8 vf1 = *(const short8*)(vrow + ((64 + g * 16) ^ sw));
      acc[0][ct] = MFMA16(pf[0][0], vf0, acc[0][ct]);
      acc[0][ct] = MFMA16(pf[0][1], vf1, acc[0][ct]);
      acc[1][ct] = MFMA16(pf[1][0], vf0, acc[1][ct]);
      acc[1][ct] = MFMA16(pf[1][1], vf1, acc[1][ct]);
    }

    __syncthreads();   // all waves done reading Vlds
    if (more) {
#pragma unroll
      for (int i = 0; i < 8; ++i) *(uint4*)&Vlds[(i * 512 + t) * 8] = stg[i];
    }
    __syncthreads();   // next V tile ready
  }

  // epilogue: normalize, store AO [B][N][C]
  float inv[2][4];
#pragma unroll
  for (int qt = 0; qt < 2; ++qt)
#pragma unroll
    for (int r = 0; r < 4; ++r) inv[qt][r] = 1.0f / l_[qt][r];
#pragma unroll
  for (int qt = 0; qt < 2; ++qt)
#pragma unroll
    for (int ct = 0; ct < 16; ++ct)
#pragma unroll
      for (int r = 0; r < 4; ++r) {
        int qrow = qbase + qt * 16 + g * 4 + r;
        int c = chb + ct * 16 + l15;
        AOb[((size_t)(b * 4096 + qrow)) * 512 + c] = f2bf(acc[qt][ct][r] * inv[qt][r]);
      }
}

// ---------------------------------------------------------------------------
// Output projection + residual: out = gamma*(Wo AO + bo) + x -> FP32 d_out
// grid = (n-tiles=64, b=8); block covers ALL 512 o (og loop), x read once.
// ---------------------------------------------------------------------------
__global__ __launch_bounds__(256) void wo_out(
    const u16* __restrict__ AOb, const u16* __restrict__ Wob,
    const float* __restrict__ bo, const float* __restrict__ gamma,
    const float* __restrict__ x, float* __restrict__ out) {
  const int b = blockIdx.y, nb = blockIdx.x * 64;
  const int t = threadIdx.x, w = t >> 6, lane = t & 63, g = lane >> 4, l15 = lane & 15;
  const int wo = (w >> 1) * 32, wn = (w & 1) * 32;

  f32x4 zero4 = {0.f, 0.f, 0.f, 0.f};
  f32x4 acc[8][2][2];
#pragma unroll
  for (int og = 0; og < 8; ++og)
#pragma unroll
    for (int ot = 0; ot < 2; ++ot)
#pragma unroll
      for (int nt = 0; nt < 2; ++nt) acc[og][ot][nt] = zero4;

  for (int c0 = 0; c0 < 512; c0 += 64) {
    short8 bb[2][2];
#pragma unroll
    for (int nt = 0; nt < 2; ++nt)
#pragma unroll
      for (int ks = 0; ks < 2; ++ks)
        bb[nt][ks] = *(const short8*)&AOb[((size_t)(b * 4096 + nb + wn + nt * 16 + l15)) * 512 + c0 + ks * 32 + g * 8];
#pragma unroll
    for (int og = 0; og < 8; ++og) {
      short8 af[2][2];
#pragma unroll
      for (int ot = 0; ot < 2; ++ot)
#pragma unroll
        for (int ks = 0; ks < 2; ++ks)
          af[ot][ks] = *(const short8*)&Wob[(size_t)(og * 64 + wo + ot * 16 + l15) * 512 + c0 + ks * 32 + g * 8];
#pragma unroll
      for (int ks = 0; ks < 2; ++ks)
#pragma unroll
        for (int ot = 0; ot < 2; ++ot)
#pragma unroll
          for (int nt = 0; nt < 2; ++nt)
            acc[og][ot][nt] = MFMA16(af[ot][ks], bb[nt][ks], acc[og][ot][nt]);
    }
  }

  float gm = gamma[0];
#pragma unroll
  for (int og = 0; og < 8; ++og)
#pragma unroll
    for (int ot = 0; ot < 2; ++ot)
#pragma unroll
      for (int nt = 0; nt < 2; ++nt)
#pragma unroll
        for (int r = 0; r < 4; ++r) {
          int o = og * 64 + wo + ot * 16 + g * 4 + r;
          int n = nb + wn + nt * 16 + l15;
          size_t idx = ((size_t)(b * 512 + o)) * 4096 + n;
          out[idx] = gm * (acc[og][ot][nt][r] + bo[o]) + x[idx];
        }
}

// ---------------------------------------------------------------------------
// Workspace map (38.8 MB):
//   AOb ws+0 (32MB) | Qb ws+32M (2MB) | Kb ws+34M (2MB) | Wvb, Wob (1MB)
//   V2 = d_out scratch (32MB inside 64MB fp32 d_out), consumed by attn3
//   before wo_out rewrites every d_out element.
// ---------------------------------------------------------------------------
extern "C" void kernel_launch(void* const* d_in, const int* in_sizes, int n_in,
                              void* d_out, int out_size, void* d_ws, size_t ws_size,
                              hipStream_t stream) {
  (void)in_sizes; (void)n_in; (void)out_size; (void)ws_size;
  const float* x     = (const float*)d_in[0];
  const float* Wq    = (const float*)d_in[1];
  const float* bq    = (const float*)d_in[2];
  const float* Wk    = (const float*)d_in[3];
  const float* bk    = (const float*)d_in[4];
  const float* Wv    = (const float*)d_in[5];
  const float* bv    = (const float*)d_in[6];
  const float* Wo    = (const float*)d_in[7];
  const float* bo    = (const float*)d_in[8];
  const float* gamma = (const float*)d_in[9];

  char* wsb = (char*)d_ws;
  u16* AOb = (u16*)(wsb + 0);
  u16* Qb  = (u16*)(wsb + (size_t)33554432);
  u16* Kb  = (u16*)(wsb + (size_t)35651584);
  u16* Wvb = (u16*)(wsb + (size_t)37748736);
  u16* Wob = (u16*)(wsb + (size_t)38273024);
  u16* V2  = (u16*)d_out;  // scratch inside fp32 d_out; rewritten by wo_out

  conv_w<<<256, 256, 0, stream>>>(Wv, Wvb, 65536);
  conv_w<<<256, 256, 0, stream>>>(Wo, Wob, 65536);
  qk_proj<<<dim3(64, 8), 256, 0, stream>>>(x, Wq, bq, Wk, bk, Qb, Kb);
  v_proj<<<dim3(64, 8), 256, 0, stream>>>(x, Wvb, bv, V2);
  attn3<<<256, 512, 0, stream>>>(Qb, Kb, V2, AOb);
  wo_out<<<dim3(64, 8), 256, 0, stream>>>(AOb, Wob, bo, gamma, x, (float*)d_out);
}

// Round 9
// 723.501 us; speedup vs baseline: 2.5598x; 1.0021x over previous
//
#include <hip/hip_runtime.h>
#include <stdint.h>

typedef unsigned short u16;
typedef float f32x4 __attribute__((ext_vector_type(4)));
typedef short short8 __attribute__((ext_vector_type(8)));  // 8 bf16 in 4 VGPRs

__device__ __forceinline__ u16 f2bf(float f) {
  union { float f; uint32_t u; } v; v.f = f;
  return (u16)((v.u + 0x7FFFu + ((v.u >> 16) & 1u)) >> 16);
}
__device__ __forceinline__ uint32_t pack2(u16 lo, u16 hi) {
  return (uint32_t)lo | ((uint32_t)hi << 16);
}

#define MFMA16(a, b, c) __builtin_amdgcn_mfma_f32_16x16x32_bf16((a), (b), (c), 0, 0, 0)

// ---------------------------------------------------------------------------
// Weight fp32 -> bf16 conversion (Wv, Wo)
// ---------------------------------------------------------------------------
__global__ void conv_w(const float* __restrict__ src, u16* __restrict__ dst, int n4) {
  int i = blockIdx.x * blockDim.x + threadIdx.x;
  if (i >= n4) return;
  float4 v = ((const float4*)src)[i];
  uint2 p;
  p.x = pack2(f2bf(v.x), f2bf(v.y));
  p.y = pack2(f2bf(v.z), f2bf(v.w));
  ((uint2*)dst)[i] = p;
}

// ---------------------------------------------------------------------------
// Q/K projection (fp32 VALU): Q scaled by log2e. Layout [B][N][32].
// ---------------------------------------------------------------------------
__global__ __launch_bounds__(256) void qk_proj(
    const float* __restrict__ x, const float* __restrict__ Wq,
    const float* __restrict__ bq, const float* __restrict__ Wk,
    const float* __restrict__ bk, u16* __restrict__ Qb, u16* __restrict__ Kb) {
  const int b = blockIdx.y, nb = blockIdx.x * 64;
  const int t = threadIdx.x;
  __shared__ __align__(16) float xs[64][64];
  __shared__ __align__(16) float ws[64][72];

  const int r0 = (t >> 4) * 4, n0 = (t & 15) * 4;
  float acc[4][4];
#pragma unroll
  for (int i = 0; i < 4; ++i)
#pragma unroll
    for (int j = 0; j < 4; ++j) acc[i][j] = 0.0f;

  for (int c0 = 0; c0 < 512; c0 += 64) {
#pragma unroll
    for (int p = 0; p < 4; ++p) {
      int idx = t + p * 256;
      int c = idx >> 4, nn = (idx & 15) * 4;
      *(float4*)&xs[c][nn] =
          *(const float4*)&x[((size_t)(b * 512 + c0 + c)) * 4096 + nb + nn];
    }
#pragma unroll
    for (int p = 0; p < 4; ++p) {
      int idx = t + p * 256;
      int r = idx >> 4, cc = (idx & 15) * 4;
      const float* Wrow = (r < 32) ? (Wq + (size_t)r * 512) : (Wk + (size_t)(r - 32) * 512);
      *(float4*)&ws[r][cc] = *(const float4*)&Wrow[c0 + cc];
    }
    __syncthreads();
    for (int c = 0; c < 64; c += 4) {
      float4 xa0 = *(const float4*)&xs[c + 0][n0];
      float4 xa1 = *(const float4*)&xs[c + 1][n0];
      float4 xa2 = *(const float4*)&xs[c + 2][n0];
      float4 xa3 = *(const float4*)&xs[c + 3][n0];
#pragma unroll
      for (int i = 0; i < 4; ++i) {
        float4 wa = *(const float4*)&ws[r0 + i][c];
        acc[i][0] += wa.x * xa0.x + wa.y * xa1.x + wa.z * xa2.x + wa.w * xa3.x;
        acc[i][1] += wa.x * xa0.y + wa.y * xa1.y + wa.z * xa2.y + wa.w * xa3.y;
        acc[i][2] += wa.x * xa0.z + wa.y * xa1.z + wa.z * xa2.z + wa.w * xa3.z;
        acc[i][3] += wa.x * xa0.w + wa.y * xa1.w + wa.z * xa2.w + wa.w * xa3.w;
      }
    }
    __syncthreads();
  }

  const float LOG2E = 1.4426950408889634f;
#pragma unroll
  for (int i = 0; i < 4; ++i) {
    int r = r0 + i;
#pragma unroll
    for (int j = 0; j < 4; ++j) {
      int n = nb + n0 + j;
      if (r < 32) {
        Qb[((size_t)(b * 4096 + n)) * 32 + r] = f2bf((acc[i][j] + bq[r]) * LOG2E);
      } else {
        Kb[((size_t)(b * 4096 + n)) * 32 + (r - 32)] = f2bf(acc[i][j] + bk[r - 32]);
      }
    }
  }
}

// ---------------------------------------------------------------------------
// V projection: V2 swizzled-tile layout for attn3 LDS staging.
//   V2 u16 index: b*2097152 + (n>>6)*32768 + c*64 + (((kk*2)^((c&7)<<4))>>1),
//   kk = n&63. grid = (n-tiles=64, b=8); block covers ALL 512 o (og loop).
// ---------------------------------------------------------------------------
__global__ __launch_bounds__(256) void v_proj(
    const float* __restrict__ x, const u16* __restrict__ Wvb,
    const float* __restrict__ bv, u16* __restrict__ V2) {
  const int b = blockIdx.y, nb = blockIdx.x * 64;
  const int t = threadIdx.x, w = t >> 6, lane = t & 63, g = lane >> 4, l15 = lane & 15;
  const int wo = (w >> 1) * 32, wn = (w & 1) * 32;
  __shared__ __align__(16) u16 xT[64][64];  // row = n (128B rows), swizzled

  f32x4 zero4 = {0.f, 0.f, 0.f, 0.f};
  f32x4 acc[8][2][2];
#pragma unroll
  for (int og = 0; og < 8; ++og)
#pragma unroll
    for (int ot = 0; ot < 2; ++ot)
#pragma unroll
      for (int nt = 0; nt < 2; ++nt) acc[og][ot][nt] = zero4;

  const int cq4 = (t >> 4) * 4, n4 = (t & 15) * 4;

  for (int c0 = 0; c0 < 512; c0 += 64) {
    float4 q0 = *(const float4*)&x[((size_t)(b * 512 + c0 + cq4 + 0)) * 4096 + nb + n4];
    float4 q1 = *(const float4*)&x[((size_t)(b * 512 + c0 + cq4 + 1)) * 4096 + nb + n4];
    float4 q2 = *(const float4*)&x[((size_t)(b * 512 + c0 + cq4 + 2)) * 4096 + nb + n4];
    float4 q3 = *(const float4*)&x[((size_t)(b * 512 + c0 + cq4 + 3)) * 4096 + nb + n4];
    float rr[4][4];
    rr[0][0] = q0.x; rr[0][1] = q0.y; rr[0][2] = q0.z; rr[0][3] = q0.w;
    rr[1][0] = q1.x; rr[1][1] = q1.y; rr[1][2] = q1.z; rr[1][3] = q1.w;
    rr[2][0] = q2.x; rr[2][1] = q2.y; rr[2][2] = q2.z; rr[2][3] = q2.w;
    rr[3][0] = q3.x; rr[3][1] = q3.y; rr[3][2] = q3.z; rr[3][3] = q3.w;
#pragma unroll
    for (int k = 0; k < 4; ++k) {
      int row = n4 + k;
      uint2 pk;
      pk.x = pack2(f2bf(rr[0][k]), f2bf(rr[1][k]));
      pk.y = pack2(f2bf(rr[2][k]), f2bf(rr[3][k]));
      int byte = row * 128 + ((cq4 * 2) ^ ((row & 7) << 4));
      *(uint2*)((char*)&xT[0][0] + byte) = pk;
    }
    __syncthreads();

    short8 bb[2][2];
#pragma unroll
    for (int nt = 0; nt < 2; ++nt)
#pragma unroll
      for (int ks = 0; ks < 2; ++ks) {
        int row = wn + nt * 16 + l15;
        int byte = row * 128 + (((ks * 64) + (g * 16)) ^ ((row & 7) << 4));
        bb[nt][ks] = *(const short8*)((const char*)&xT[0][0] + byte);
      }
#pragma unroll
    for (int og = 0; og < 8; ++og) {
      short8 af[2][2];
#pragma unroll
      for (int ot = 0; ot < 2; ++ot)
#pragma unroll
        for (int ks = 0; ks < 2; ++ks)
          af[ot][ks] = *(const short8*)&Wvb[(size_t)(og * 64 + wo + ot * 16 + l15) * 512 + c0 + ks * 32 + g * 8];
#pragma unroll
      for (int ks = 0; ks < 2; ++ks)
#pragma unroll
        for (int ot = 0; ot < 2; ++ot)
#pragma unroll
          for (int nt = 0; nt < 2; ++nt)
            acc[og][ot][nt] = MFMA16(af[ot][ks], bb[nt][ks], acc[og][ot][nt]);
    }
    __syncthreads();
  }

  const size_t tbase = (size_t)b * 2097152 + (size_t)(nb >> 6) * 32768;
#pragma unroll
  for (int og = 0; og < 8; ++og)
#pragma unroll
    for (int ot = 0; ot < 2; ++ot)
#pragma unroll
      for (int nt = 0; nt < 2; ++nt)
#pragma unroll
        for (int r = 0; r < 4; ++r) {
          int o = og * 64 + wo + ot * 16 + g * 4 + r;
          int kk = wn + nt * 16 + l15;
          int swz = ((kk * 2) ^ ((o & 7) << 4)) >> 1;
          V2[tbase + o * 64 + swz] = f2bf(acc[og][ot][nt][r] + bv[o]);
        }
}

// ---------------------------------------------------------------------------
// Flash attention v3: block = 128 q-rows x 512 ch, 8 waves (32q x 256ch each).
// grid = 256 (1 block/CU), batch = bid&7 (XCD-pinned). V tile (64 keys, all
// 512 ch, 64KB) staged once per block into LDS (swizzled), shared by 8 waves.
// Async staging: global->reg before S/softmax, ds_write after PV barrier.
// launch_bounds(512,1): VGPR cap 256 — (512,2) capped at 128 and spilled
// the 128-reg accumulator to scratch (round 8: WRITE_SIZE 480MB, VGPR 120).
// ---------------------------------------------------------------------------
__global__ __launch_bounds__(512, 1) void attn3(
    const u16* __restrict__ Qb, const u16* __restrict__ Kb,
    const u16* __restrict__ V2, u16* __restrict__ AOb) {
  const int bid = blockIdx.x;
  const int b = bid & 7;
  const int qblk = (bid >> 3) * 128;
  const int t = threadIdx.x;
  const int w = t >> 6, lane = t & 63, g = lane >> 4, l15 = lane & 15;
  const int qbase = qblk + (w >> 1) * 32;   // 4 q-groups of 32 rows
  const int chb = (w & 1) * 256;            // 2 channel halves

  __shared__ __align__(16) u16 Vlds[32768];      // [512 ch][64 keys] swizzled
  __shared__ __align__(16) u16 Plds[8][32][88];  // wave-private P, 176B rows

  f32x4 zero4 = {0.f, 0.f, 0.f, 0.f};

  short8 qf[2];
#pragma unroll
  for (int qt = 0; qt < 2; ++qt)
    qf[qt] = *(const short8*)&Qb[((size_t)(b * 4096 + qbase + qt * 16 + l15)) * 32 + g * 8];

  f32x4 acc[2][16];
#pragma unroll
  for (int qt = 0; qt < 2; ++qt)
#pragma unroll
    for (int ct = 0; ct < 16; ++ct) acc[qt][ct] = zero4;
  float l_[2][4] = {{0.f, 0.f, 0.f, 0.f}, {0.f, 0.f, 0.f, 0.f}};

  const u16* VB = V2 + (size_t)b * 2097152;
  const size_t kb0 = (size_t)b * 4096;

  // prologue: stage V tile 0
#pragma unroll
  for (int i = 0; i < 8; ++i) {
    uint4 v = *(const uint4*)&VB[(i * 512 + t) * 8];
    *(uint4*)&Vlds[(i * 512 + t) * 8] = v;
  }
  __syncthreads();

  for (int kv = 0; kv < 4096; kv += 64) {
    const bool more = (kv + 64) < 4096;
    uint4 stg[8];
    if (more) {
      const u16* Vt = VB + (size_t)((kv >> 6) + 1) * 32768;
#pragma unroll
      for (int i = 0; i < 8; ++i) stg[i] = *(const uint4*)&Vt[(i * 512 + t) * 8];
    }

    // S: 32 q-rows x 64 keys (4 slices)
    f32x4 s[2][4];
#pragma unroll
    for (int ks = 0; ks < 4; ++ks) {
      short8 kf = *(const short8*)&Kb[(kb0 + kv + ks * 16 + l15) * 32 + g * 8];
      s[0][ks] = MFMA16(qf[0], kf, zero4);
      s[1][ks] = MFMA16(qf[1], kf, zero4);
    }

    // p = 2^s, row sums, P to wave-private LDS (transpose)
#pragma unroll
    for (int qt = 0; qt < 2; ++qt)
#pragma unroll
      for (int r = 0; r < 4; ++r) {
        float rs = 0.f;
#pragma unroll
        for (int ks = 0; ks < 4; ++ks) {
          float p = exp2f(s[qt][ks][r]);
          rs += p;
          Plds[w][qt * 16 + g * 4 + r][ks * 16 + l15] = f2bf(p);
        }
        rs += __shfl_xor(rs, 1);
        rs += __shfl_xor(rs, 2);
        rs += __shfl_xor(rs, 4);
        rs += __shfl_xor(rs, 8);
        l_[qt][r] += rs;
      }

    // PV: V from swizzled LDS (shared), P from wave-private LDS
    short8 pf[2][2];
#pragma unroll
    for (int qt = 0; qt < 2; ++qt)
#pragma unroll
      for (int k2 = 0; k2 < 2; ++k2)
        pf[qt][k2] = *(const short8*)&Plds[w][qt * 16 + l15][k2 * 32 + g * 8];
#pragma unroll
    for (int ct = 0; ct < 16; ++ct) {
      int c = chb + ct * 16 + l15;
      int sw = (c & 7) << 4;
      const char* vrow = (const char*)&Vlds[0] + c * 128;
      short8 vf0 = *(const short8*)(vrow + ((g * 16) ^ sw));
      short8 vf1 = *(const short8*)(vrow + ((64 + g * 16) ^ sw));
      acc[0][ct] = MFMA16(pf[0][0], vf0, acc[0][ct]);
      acc[0][ct] = MFMA16(pf[0][1], vf1, acc[0][ct]);
      acc[1][ct] = MFMA16(pf[1][0], vf0, acc[1][ct]);
      acc[1][ct] = MFMA16(pf[1][1], vf1, acc[1][ct]);
    }

    __syncthreads();   // all waves done reading Vlds
    if (more) {
#pragma unroll
      for (int i = 0; i < 8; ++i) *(uint4*)&Vlds[(i * 512 + t) * 8] = stg[i];
    }
    __syncthreads();   // next V tile ready
  }

  // epilogue: normalize, store AO [B][N][C]
  float inv[2][4];
#pragma unroll
  for (int qt = 0; qt < 2; ++qt)
#pragma unroll
    for (int r = 0; r < 4; ++r) inv[qt][r] = 1.0f / l_[qt][r];
#pragma unroll
  for (int qt = 0; qt < 2; ++qt)
#pragma unroll
    for (int ct = 0; ct < 16; ++ct)
#pragma unroll
      for (int r = 0; r < 4; ++r) {
        int qrow = qbase + qt * 16 + g * 4 + r;
        int c = chb + ct * 16 + l15;
        AOb[((size_t)(b * 4096 + qrow)) * 512 + c] = f2bf(acc[qt][ct][r] * inv[qt][r]);
      }
}

// ---------------------------------------------------------------------------
// Output projection + residual: out = gamma*(Wo AO + bo) + x -> FP32 d_out
// grid = (n-tiles=64, b=8); block covers ALL 512 o (og loop), x read once.
// ---------------------------------------------------------------------------
__global__ __launch_bounds__(256) void wo_out(
    const u16* __restrict__ AOb, const u16* __restrict__ Wob,
    const float* __restrict__ bo, const float* __restrict__ gamma,
    const float* __restrict__ x, float* __restrict__ out) {
  const int b = blockIdx.y, nb = blockIdx.x * 64;
  const int t = threadIdx.x, w = t >> 6, lane = t & 63, g = lane >> 4, l15 = lane & 15;
  const int wo = (w >> 1) * 32, wn = (w & 1) * 32;

  f32x4 zero4 = {0.f, 0.f, 0.f, 0.f};
  f32x4 acc[8][2][2];
#pragma unroll
  for (int og = 0; og < 8; ++og)
#pragma unroll
    for (int ot = 0; ot < 2; ++ot)
#pragma unroll
      for (int nt = 0; nt < 2; ++nt) acc[og][ot][nt] = zero4;

  for (int c0 = 0; c0 < 512; c0 += 64) {
    short8 bb[2][2];
#pragma unroll
    for (int nt = 0; nt < 2; ++nt)
#pragma unroll
      for (int ks = 0; ks < 2; ++ks)
        bb[nt][ks] = *(const short8*)&AOb[((size_t)(b * 4096 + nb + wn + nt * 16 + l15)) * 512 + c0 + ks * 32 + g * 8];
#pragma unroll
    for (int og = 0; og < 8; ++og) {
      short8 af[2][2];
#pragma unroll
      for (int ot = 0; ot < 2; ++ot)
#pragma unroll
        for (int ks = 0; ks < 2; ++ks)
          af[ot][ks] = *(const short8*)&Wob[(size_t)(og * 64 + wo + ot * 16 + l15) * 512 + c0 + ks * 32 + g * 8];
#pragma unroll
      for (int ks = 0; ks < 2; ++ks)
#pragma unroll
        for (int ot = 0; ot < 2; ++ot)
#pragma unroll
          for (int nt = 0; nt < 2; ++nt)
            acc[og][ot][nt] = MFMA16(af[ot][ks], bb[nt][ks], acc[og][ot][nt]);
    }
  }

  float gm = gamma[0];
#pragma unroll
  for (int og = 0; og < 8; ++og)
#pragma unroll
    for (int ot = 0; ot < 2; ++ot)
#pragma unroll
      for (int nt = 0; nt < 2; ++nt)
#pragma unroll
        for (int r = 0; r < 4; ++r) {
          int o = og * 64 + wo + ot * 16 + g * 4 + r;
          int n = nb + wn + nt * 16 + l15;
          size_t idx = ((size_t)(b * 512 + o)) * 4096 + n;
          out[idx] = gm * (acc[og][ot][nt][r] + bo[o]) + x[idx];
        }
}

// ---------------------------------------------------------------------------
// Workspace map (38.8 MB):
//   AOb ws+0 (32MB) | Qb ws+32M (2MB) | Kb ws+34M (2MB) | Wvb, Wob (1MB)
//   V2 = d_out scratch (32MB inside 64MB fp32 d_out), consumed by attn3
//   before wo_out rewrites every d_out element.
// ---------------------------------------------------------------------------
extern "C" void kernel_launch(void* const* d_in, const int* in_sizes, int n_in,
                              void* d_out, int out_size, void* d_ws, size_t ws_size,
                              hipStream_t stream) {
  (void)in_sizes; (void)n_in; (void)out_size; (void)ws_size;
  const float* x     = (const float*)d_in[0];
  const float* Wq    = (const float*)d_in[1];
  const float* bq    = (const float*)d_in[2];
  const float* Wk    = (const float*)d_in[3];
  const float* bk    = (const float*)d_in[4];
  const float* Wv    = (const float*)d_in[5];
  const float* bv    = (const float*)d_in[6];
  const float* Wo    = (const float*)d_in[7];
  const float* bo    = (const float*)d_in[8];
  const float* gamma = (const float*)d_in[9];

  char* wsb = (char*)d_ws;
  u16* AOb = (u16*)(wsb + 0);
  u16* Qb  = (u16*)(wsb + (size_t)33554432);
  u16* Kb  = (u16*)(wsb + (size_t)35651584);
  u16* Wvb = (u16*)(wsb + (size_t)37748736);
  u16* Wob = (u16*)(wsb + (size_t)38273024);
  u16* V2  = (u16*)d_out;  // scratch inside fp32 d_out; rewritten by wo_out

  conv_w<<<256, 256, 0, stream>>>(Wv, Wvb, 65536);
  conv_w<<<256, 256, 0, stream>>>(Wo, Wob, 65536);
  qk_proj<<<dim3(64, 8), 256, 0, stream>>>(x, Wq, bq, Wk, bk, Qb, Kb);
  v_proj<<<dim3(64, 8), 256, 0, stream>>>(x, Wvb, bv, V2);
  attn3<<<256, 512, 0, stream>>>(Qb, Kb, V2, AOb);
  wo_out<<<dim3(64, 8), 256, 0, stream>>>(AOb, Wob, bo, gamma, x, (float*)d_out);
}

// Round 10
// 647.950 us; speedup vs baseline: 2.8582x; 1.1166x over previous
//
#include <hip/hip_runtime.h>
#include <stdint.h>

typedef unsigned short u16;
typedef float f32x4 __attribute__((ext_vector_type(4)));
typedef short short8 __attribute__((ext_vector_type(8)));  // 8 bf16 in 4 VGPRs

__device__ __forceinline__ u16 f2bf(float f) {
  union { float f; uint32_t u; } v; v.f = f;
  return (u16)((v.u + 0x7FFFu + ((v.u >> 16) & 1u)) >> 16);
}
__device__ __forceinline__ uint32_t pack2(u16 lo, u16 hi) {
  return (uint32_t)lo | ((uint32_t)hi << 16);
}

#define MFMA16(a, b, c) __builtin_amdgcn_mfma_f32_16x16x32_bf16((a), (b), (c), 0, 0, 0)

// ---------------------------------------------------------------------------
// Weight fp32 -> bf16 conversion (Wv, Wo)
// ---------------------------------------------------------------------------
__global__ void conv_w(const float* __restrict__ src, u16* __restrict__ dst, int n4) {
  int i = blockIdx.x * blockDim.x + threadIdx.x;
  if (i >= n4) return;
  float4 v = ((const float4*)src)[i];
  uint2 p;
  p.x = pack2(f2bf(v.x), f2bf(v.y));
  p.y = pack2(f2bf(v.z), f2bf(v.w));
  ((uint2*)dst)[i] = p;
}

// ---------------------------------------------------------------------------
// Q/K projection (fp32 VALU): Q scaled by log2e. Layout [B][N][32].
// ---------------------------------------------------------------------------
__global__ __launch_bounds__(256) void qk_proj(
    const float* __restrict__ x, const float* __restrict__ Wq,
    const float* __restrict__ bq, const float* __restrict__ Wk,
    const float* __restrict__ bk, u16* __restrict__ Qb, u16* __restrict__ Kb) {
  const int b = blockIdx.y, nb = blockIdx.x * 64;
  const int t = threadIdx.x;
  __shared__ __align__(16) float xs[64][64];
  __shared__ __align__(16) float ws[64][72];

  const int r0 = (t >> 4) * 4, n0 = (t & 15) * 4;
  float acc[4][4];
#pragma unroll
  for (int i = 0; i < 4; ++i)
#pragma unroll
    for (int j = 0; j < 4; ++j) acc[i][j] = 0.0f;

  for (int c0 = 0; c0 < 512; c0 += 64) {
#pragma unroll
    for (int p = 0; p < 4; ++p) {
      int idx = t + p * 256;
      int c = idx >> 4, nn = (idx & 15) * 4;
      *(float4*)&xs[c][nn] =
          *(const float4*)&x[((size_t)(b * 512 + c0 + c)) * 4096 + nb + nn];
    }
#pragma unroll
    for (int p = 0; p < 4; ++p) {
      int idx = t + p * 256;
      int r = idx >> 4, cc = (idx & 15) * 4;
      const float* Wrow = (r < 32) ? (Wq + (size_t)r * 512) : (Wk + (size_t)(r - 32) * 512);
      *(float4*)&ws[r][cc] = *(const float4*)&Wrow[c0 + cc];
    }
    __syncthreads();
    for (int c = 0; c < 64; c += 4) {
      float4 xa0 = *(const float4*)&xs[c + 0][n0];
      float4 xa1 = *(const float4*)&xs[c + 1][n0];
      float4 xa2 = *(const float4*)&xs[c + 2][n0];
      float4 xa3 = *(const float4*)&xs[c + 3][n0];
#pragma unroll
      for (int i = 0; i < 4; ++i) {
        float4 wa = *(const float4*)&ws[r0 + i][c];
        acc[i][0] += wa.x * xa0.x + wa.y * xa1.x + wa.z * xa2.x + wa.w * xa3.x;
        acc[i][1] += wa.x * xa0.y + wa.y * xa1.y + wa.z * xa2.y + wa.w * xa3.y;
        acc[i][2] += wa.x * xa0.z + wa.y * xa1.z + wa.z * xa2.z + wa.w * xa3.z;
        acc[i][3] += wa.x * xa0.w + wa.y * xa1.w + wa.z * xa2.w + wa.w * xa3.w;
      }
    }
    __syncthreads();
  }

  const float LOG2E = 1.4426950408889634f;
#pragma unroll
  for (int i = 0; i < 4; ++i) {
    int r = r0 + i;
#pragma unroll
    for (int j = 0; j < 4; ++j) {
      int n = nb + n0 + j;
      if (r < 32) {
        Qb[((size_t)(b * 4096 + n)) * 32 + r] = f2bf((acc[i][j] + bq[r]) * LOG2E);
      } else {
        Kb[((size_t)(b * 4096 + n)) * 32 + (r - 32)] = f2bf(acc[i][j] + bk[r - 32]);
      }
    }
  }
}

// ---------------------------------------------------------------------------
// V projection: V2 swizzled-tile layout for attn LDS staging.
//   V2 u16 index: b*2097152 + (n>>6)*32768 + c*64 + (((kk*2)^((c&7)<<4))>>1),
//   kk = n&63. grid = (n-tiles=64, b=8); block covers ALL 512 o (og loop).
// ---------------------------------------------------------------------------
__global__ __launch_bounds__(256) void v_proj(
    const float* __restrict__ x, const u16* __restrict__ Wvb,
    const float* __restrict__ bv, u16* __restrict__ V2) {
  const int b = blockIdx.y, nb = blockIdx.x * 64;
  const int t = threadIdx.x, w = t >> 6, lane = t & 63, g = lane >> 4, l15 = lane & 15;
  const int wo = (w >> 1) * 32, wn = (w & 1) * 32;
  __shared__ __align__(16) u16 xT[64][64];  // row = n (128B rows), swizzled

  f32x4 zero4 = {0.f, 0.f, 0.f, 0.f};
  f32x4 acc[8][2][2];
#pragma unroll
  for (int og = 0; og < 8; ++og)
#pragma unroll
    for (int ot = 0; ot < 2; ++ot)
#pragma unroll
      for (int nt = 0; nt < 2; ++nt) acc[og][ot][nt] = zero4;

  const int cq4 = (t >> 4) * 4, n4 = (t & 15) * 4;

  for (int c0 = 0; c0 < 512; c0 += 64) {
    float4 q0 = *(const float4*)&x[((size_t)(b * 512 + c0 + cq4 + 0)) * 4096 + nb + n4];
    float4 q1 = *(const float4*)&x[((size_t)(b * 512 + c0 + cq4 + 1)) * 4096 + nb + n4];
    float4 q2 = *(const float4*)&x[((size_t)(b * 512 + c0 + cq4 + 2)) * 4096 + nb + n4];
    float4 q3 = *(const float4*)&x[((size_t)(b * 512 + c0 + cq4 + 3)) * 4096 + nb + n4];
    float rr[4][4];
    rr[0][0] = q0.x; rr[0][1] = q0.y; rr[0][2] = q0.z; rr[0][3] = q0.w;
    rr[1][0] = q1.x; rr[1][1] = q1.y; rr[1][2] = q1.z; rr[1][3] = q1.w;
    rr[2][0] = q2.x; rr[2][1] = q2.y; rr[2][2] = q2.z; rr[2][3] = q2.w;
    rr[3][0] = q3.x; rr[3][1] = q3.y; rr[3][2] = q3.z; rr[3][3] = q3.w;
#pragma unroll
    for (int k = 0; k < 4; ++k) {
      int row = n4 + k;
      uint2 pk;
      pk.x = pack2(f2bf(rr[0][k]), f2bf(rr[1][k]));
      pk.y = pack2(f2bf(rr[2][k]), f2bf(rr[3][k]));
      int byte = row * 128 + ((cq4 * 2) ^ ((row & 7) << 4));
      *(uint2*)((char*)&xT[0][0] + byte) = pk;
    }
    __syncthreads();

    short8 bb[2][2];
#pragma unroll
    for (int nt = 0; nt < 2; ++nt)
#pragma unroll
      for (int ks = 0; ks < 2; ++ks) {
        int row = wn + nt * 16 + l15;
        int byte = row * 128 + (((ks * 64) + (g * 16)) ^ ((row & 7) << 4));
        bb[nt][ks] = *(const short8*)((const char*)&xT[0][0] + byte);
      }
#pragma unroll
    for (int og = 0; og < 8; ++og) {
      short8 af[2][2];
#pragma unroll
      for (int ot = 0; ot < 2; ++ot)
#pragma unroll
        for (int ks = 0; ks < 2; ++ks)
          af[ot][ks] = *(const short8*)&Wvb[(size_t)(og * 64 + wo + ot * 16 + l15) * 512 + c0 + ks * 32 + g * 8];
#pragma unroll
      for (int ks = 0; ks < 2; ++ks)
#pragma unroll
        for (int ot = 0; ot < 2; ++ot)
#pragma unroll
          for (int nt = 0; nt < 2; ++nt)
            acc[og][ot][nt] = MFMA16(af[ot][ks], bb[nt][ks], acc[og][ot][nt]);
    }
    __syncthreads();
  }

  const size_t tbase = (size_t)b * 2097152 + (size_t)(nb >> 6) * 32768;
#pragma unroll
  for (int og = 0; og < 8; ++og)
#pragma unroll
    for (int ot = 0; ot < 2; ++ot)
#pragma unroll
      for (int nt = 0; nt < 2; ++nt)
#pragma unroll
        for (int r = 0; r < 4; ++r) {
          int o = og * 64 + wo + ot * 16 + g * 4 + r;
          int kk = wn + nt * 16 + l15;
          int swz = ((kk * 2) ^ ((o & 7) << 4)) >> 1;
          V2[tbase + o * 64 + swz] = f2bf(acc[og][ot][nt][r] + bv[o]);
        }
}

// ---------------------------------------------------------------------------
// Flash attention v4: block = 128q x 512ch, 8 waves. Wave pair (qg=w&3,
// chh=w>>2): chh0 computes S+softmax into SHARED Plds[qg]; both halves do PV.
// Vlds double-buffered (2x64KB): stage copy global->reg->LDS within one phase
// (short stg live range — round 8/9's 480MB scratch spill came from stg
// spanning the whole iteration). lsum LDS exchange for normalization.
// ---------------------------------------------------------------------------
__global__ __launch_bounds__(512, 1) void attn4(
    const u16* __restrict__ Qb, const u16* __restrict__ Kb,
    const u16* __restrict__ V2, u16* __restrict__ AOb) {
  const int bid = blockIdx.x;
  const int b = bid & 7;                 // XCD-pinned batch
  const int qblk = (bid >> 3) * 128;
  const int t = threadIdx.x;
  const int w = t >> 6, lane = t & 63, g = lane >> 4, l15 = lane & 15;
  const int qg = w & 3, chh = w >> 2;    // SIMD i hosts (qg=i,chh=0)+(qg=i,chh=1)
  const int qbase = qblk + qg * 32;
  const int chb = chh * 256;

  __shared__ __align__(16) u16 Vlds[2][32768];   // [buf][512ch][64k] swizzled
  __shared__ __align__(16) u16 Plds[4][32][88];  // per q-group, shared
  __shared__ float lsum[4][32];

  f32x4 zero4 = {0.f, 0.f, 0.f, 0.f};

  short8 qf[2];
  if (chh == 0) {
#pragma unroll
    for (int qt = 0; qt < 2; ++qt)
      qf[qt] = *(const short8*)&Qb[((size_t)(b * 4096 + qbase + qt * 16 + l15)) * 32 + g * 8];
  }

  f32x4 acc[2][16];
#pragma unroll
  for (int qt = 0; qt < 2; ++qt)
#pragma unroll
    for (int ct = 0; ct < 16; ++ct) acc[qt][ct] = zero4;
  float l_[2][4] = {{0.f, 0.f, 0.f, 0.f}, {0.f, 0.f, 0.f, 0.f}};

  const u16* VB = V2 + (size_t)b * 2097152;
  const size_t kb0 = (size_t)b * 4096;

  // prologue: stage V tile 0 into buf 0
#pragma unroll
  for (int i = 0; i < 8; ++i) {
    uint4 v = *(const uint4*)&VB[(i * 512 + t) * 8];
    *(uint4*)&Vlds[0][(i * 512 + t) * 8] = v;
  }
  __syncthreads();

  for (int kv = 0; kv < 4096; kv += 64) {
    const int buf = (kv >> 6) & 1;
    const bool more = (kv + 64) < 4096;

    // 1) issue next-tile loads (landing in regs only briefly)
    uint4 stg[8];
    if (more) {
      const u16* Vt = VB + (size_t)((kv >> 6) + 1) * 32768;
#pragma unroll
      for (int i = 0; i < 8; ++i) stg[i] = *(const uint4*)&Vt[(i * 512 + t) * 8];
    }

    // 2) S (chh0 only): 32q x 64 keys
    f32x4 s[2][4];
    if (chh == 0) {
#pragma unroll
      for (int ks = 0; ks < 4; ++ks) {
        short8 kf = *(const short8*)&Kb[(kb0 + kv + ks * 16 + l15) * 32 + g * 8];
        s[0][ks] = MFMA16(qf[0], kf, zero4);
        s[1][ks] = MFMA16(qf[1], kf, zero4);
      }
    }

    // 3) retire staged tile into the other buffer (ends stg's live range)
    if (more) {
#pragma unroll
      for (int i = 0; i < 8; ++i) *(uint4*)&Vlds[buf ^ 1][(i * 512 + t) * 8] = stg[i];
    }

    // 4) softmax (chh0 only): p = 2^s, row sums, P -> shared Plds[qg]
    if (chh == 0) {
#pragma unroll
      for (int qt = 0; qt < 2; ++qt)
#pragma unroll
        for (int r = 0; r < 4; ++r) {
          float rs = 0.f;
#pragma unroll
          for (int ks = 0; ks < 4; ++ks) {
            float p = exp2f(s[qt][ks][r]);
            rs += p;
            Plds[qg][qt * 16 + g * 4 + r][ks * 16 + l15] = f2bf(p);
          }
          rs += __shfl_xor(rs, 1);
          rs += __shfl_xor(rs, 2);
          rs += __shfl_xor(rs, 4);
          rs += __shfl_xor(rs, 8);
          l_[qt][r] += rs;
        }
    }
    __syncthreads();   // P(t) visible, V(t+1) written

    // 5) PV: both ch-halves, V from Vlds[buf], P from Plds[qg]
    short8 pf[2][2];
#pragma unroll
    for (int qt = 0; qt < 2; ++qt)
#pragma unroll
      for (int k2 = 0; k2 < 2; ++k2)
        pf[qt][k2] = *(const short8*)&Plds[qg][qt * 16 + l15][k2 * 32 + g * 8];
#pragma unroll
    for (int ct = 0; ct < 16; ++ct) {
      int c = chb + ct * 16 + l15;
      int sw = (c & 7) << 4;
      const char* vrow = (const char*)&Vlds[buf][0] + c * 128;
      short8 vf0 = *(const short8*)(vrow + ((g * 16) ^ sw));
      short8 vf1 = *(const short8*)(vrow + ((64 + g * 16) ^ sw));
      acc[0][ct] = MFMA16(pf[0][0], vf0, acc[0][ct]);
      acc[0][ct] = MFMA16(pf[0][1], vf1, acc[0][ct]);
      acc[1][ct] = MFMA16(pf[1][0], vf0, acc[1][ct]);
      acc[1][ct] = MFMA16(pf[1][1], vf1, acc[1][ct]);
    }
    __syncthreads();   // PV reads done before next iter's P/V writes
  }

  // epilogue: share row sums, normalize, store AO [B][N][C]
  if (chh == 0 && l15 == 0) {
#pragma unroll
    for (int qt = 0; qt < 2; ++qt)
#pragma unroll
      for (int r = 0; r < 4; ++r)
        lsum[qg][qt * 16 + g * 4 + r] = l_[qt][r];
  }
  __syncthreads();

#pragma unroll
  for (int qt = 0; qt < 2; ++qt) {
    float inv[4];
#pragma unroll
    for (int r = 0; r < 4; ++r) inv[r] = 1.0f / lsum[qg][qt * 16 + g * 4 + r];
#pragma unroll
    for (int ct = 0; ct < 16; ++ct)
#pragma unroll
      for (int r = 0; r < 4; ++r) {
        int qrow = qbase + qt * 16 + g * 4 + r;
        int c = chb + ct * 16 + l15;
        AOb[((size_t)(b * 4096 + qrow)) * 512 + c] = f2bf(acc[qt][ct][r] * inv[r]);
      }
  }
}

// ---------------------------------------------------------------------------
// Output projection + residual: out = gamma*(Wo AO + bo) + x -> FP32 d_out
// grid = (n-tiles=64, b=8); block covers ALL 512 o (og loop), x read once.
// ---------------------------------------------------------------------------
__global__ __launch_bounds__(256) void wo_out(
    const u16* __restrict__ AOb, const u16* __restrict__ Wob,
    const float* __restrict__ bo, const float* __restrict__ gamma,
    const float* __restrict__ x, float* __restrict__ out) {
  const int b = blockIdx.y, nb = blockIdx.x * 64;
  const int t = threadIdx.x, w = t >> 6, lane = t & 63, g = lane >> 4, l15 = lane & 15;
  const int wo = (w >> 1) * 32, wn = (w & 1) * 32;

  f32x4 zero4 = {0.f, 0.f, 0.f, 0.f};
  f32x4 acc[8][2][2];
#pragma unroll
  for (int og = 0; og < 8; ++og)
#pragma unroll
    for (int ot = 0; ot < 2; ++ot)
#pragma unroll
      for (int nt = 0; nt < 2; ++nt) acc[og][ot][nt] = zero4;

  for (int c0 = 0; c0 < 512; c0 += 64) {
    short8 bb[2][2];
#pragma unroll
    for (int nt = 0; nt < 2; ++nt)
#pragma unroll
      for (int ks = 0; ks < 2; ++ks)
        bb[nt][ks] = *(const short8*)&AOb[((size_t)(b * 4096 + nb + wn + nt * 16 + l15)) * 512 + c0 + ks * 32 + g * 8];
#pragma unroll
    for (int og = 0; og < 8; ++og) {
      short8 af[2][2];
#pragma unroll
      for (int ot = 0; ot < 2; ++ot)
#pragma unroll
        for (int ks = 0; ks < 2; ++ks)
          af[ot][ks] = *(const short8*)&Wob[(size_t)(og * 64 + wo + ot * 16 + l15) * 512 + c0 + ks * 32 + g * 8];
#pragma unroll
      for (int ks = 0; ks < 2; ++ks)
#pragma unroll
        for (int ot = 0; ot < 2; ++ot)
#pragma unroll
          for (int nt = 0; nt < 2; ++nt)
            acc[og][ot][nt] = MFMA16(af[ot][ks], bb[nt][ks], acc[og][ot][nt]);
    }
  }

  float gm = gamma[0];
#pragma unroll
  for (int og = 0; og < 8; ++og)
#pragma unroll
    for (int ot = 0; ot < 2; ++ot)
#pragma unroll
      for (int nt = 0; nt < 2; ++nt)
#pragma unroll
        for (int r = 0; r < 4; ++r) {
          int o = og * 64 + wo + ot * 16 + g * 4 + r;
          int n = nb + wn + nt * 16 + l15;
          size_t idx = ((size_t)(b * 512 + o)) * 4096 + n;
          out[idx] = gm * (acc[og][ot][nt][r] + bo[o]) + x[idx];
        }
}

// ---------------------------------------------------------------------------
// Workspace map (38.8 MB):
//   AOb ws+0 (32MB) | Qb ws+32M (2MB) | Kb ws+34M (2MB) | Wvb, Wob (1MB)
//   V2 = d_out scratch (32MB inside 64MB fp32 d_out), consumed by attn4
//   before wo_out rewrites every d_out element.
// ---------------------------------------------------------------------------
extern "C" void kernel_launch(void* const* d_in, const int* in_sizes, int n_in,
                              void* d_out, int out_size, void* d_ws, size_t ws_size,
                              hipStream_t stream) {
  (void)in_sizes; (void)n_in; (void)out_size; (void)ws_size;
  const float* x     = (const float*)d_in[0];
  const float* Wq    = (const float*)d_in[1];
  const float* bq    = (const float*)d_in[2];
  const float* Wk    = (const float*)d_in[3];
  const float* bk    = (const float*)d_in[4];
  const float* Wv    = (const float*)d_in[5];
  const float* bv    = (const float*)d_in[6];
  const float* Wo    = (const float*)d_in[7];
  const float* bo    = (const float*)d_in[8];
  const float* gamma = (const float*)d_in[9];

  char* wsb = (char*)d_ws;
  u16* AOb = (u16*)(wsb + 0);
  u16* Qb  = (u16*)(wsb + (size_t)33554432);
  u16* Kb  = (u16*)(wsb + (size_t)35651584);
  u16* Wvb = (u16*)(wsb + (size_t)37748736);
  u16* Wob = (u16*)(wsb + (size_t)38273024);
  u16* V2  = (u16*)d_out;  // scratch inside fp32 d_out; rewritten by wo_out

  conv_w<<<256, 256, 0, stream>>>(Wv, Wvb, 65536);
  conv_w<<<256, 256, 0, stream>>>(Wo, Wob, 65536);
  qk_proj<<<dim3(64, 8), 256, 0, stream>>>(x, Wq, bq, Wk, bk, Qb, Kb);
  v_proj<<<dim3(64, 8), 256, 0, stream>>>(x, Wvb, bv, V2);
  attn4<<<256, 512, 0, stream>>>(Qb, Kb, V2, AOb);
  wo_out<<<dim3(64, 8), 256, 0, stream>>>(AOb, Wob, bo, gamma, x, (float*)d_out);
}

// Round 11
// 503.842 us; speedup vs baseline: 3.6757x; 1.2860x over previous
//
#include <hip/hip_runtime.h>
#include <stdint.h>

typedef unsigned short u16;
typedef float f32x4 __attribute__((ext_vector_type(4)));
typedef short short8 __attribute__((ext_vector_type(8)));  // 8 bf16 in 4 VGPRs

__device__ __forceinline__ u16 f2bf(float f) {
  union { float f; uint32_t u; } v; v.f = f;
  return (u16)((v.u + 0x7FFFu + ((v.u >> 16) & 1u)) >> 16);
}
__device__ __forceinline__ uint32_t pack2(u16 lo, u16 hi) {
  return (uint32_t)lo | ((uint32_t)hi << 16);
}
// Async global->LDS DMA, 16B/lane: LDS dest = wave-uniform base + lane*16,
// global src = per-lane address. Zero VGPR staging (kills round 8-10 spill).
__device__ __forceinline__ void gld_lds16(const void* gsrc, void* ldst) {
  __builtin_amdgcn_global_load_lds(
      (const __attribute__((address_space(1))) unsigned int*)gsrc,
      (__attribute__((address_space(3))) unsigned int*)ldst, 16, 0, 0);
}

#define MFMA16(a, b, c) __builtin_amdgcn_mfma_f32_16x16x32_bf16((a), (b), (c), 0, 0, 0)

// ---------------------------------------------------------------------------
// Weight fp32 -> bf16 conversion (Wv, Wo)
// ---------------------------------------------------------------------------
__global__ void conv_w(const float* __restrict__ src, u16* __restrict__ dst, int n4) {
  int i = blockIdx.x * blockDim.x + threadIdx.x;
  if (i >= n4) return;
  float4 v = ((const float4*)src)[i];
  uint2 p;
  p.x = pack2(f2bf(v.x), f2bf(v.y));
  p.y = pack2(f2bf(v.z), f2bf(v.w));
  ((uint2*)dst)[i] = p;
}

// ---------------------------------------------------------------------------
// Q/K projection (fp32 VALU): Q scaled by log2e. Layout [B][N][32].
// ---------------------------------------------------------------------------
__global__ __launch_bounds__(256) void qk_proj(
    const float* __restrict__ x, const float* __restrict__ Wq,
    const float* __restrict__ bq, const float* __restrict__ Wk,
    const float* __restrict__ bk, u16* __restrict__ Qb, u16* __restrict__ Kb) {
  const int b = blockIdx.y, nb = blockIdx.x * 64;
  const int t = threadIdx.x;
  __shared__ __align__(16) float xs[64][64];
  __shared__ __align__(16) float ws[64][72];

  const int r0 = (t >> 4) * 4, n0 = (t & 15) * 4;
  float acc[4][4];
#pragma unroll
  for (int i = 0; i < 4; ++i)
#pragma unroll
    for (int j = 0; j < 4; ++j) acc[i][j] = 0.0f;

  for (int c0 = 0; c0 < 512; c0 += 64) {
#pragma unroll
    for (int p = 0; p < 4; ++p) {
      int idx = t + p * 256;
      int c = idx >> 4, nn = (idx & 15) * 4;
      *(float4*)&xs[c][nn] =
          *(const float4*)&x[((size_t)(b * 512 + c0 + c)) * 4096 + nb + nn];
    }
#pragma unroll
    for (int p = 0; p < 4; ++p) {
      int idx = t + p * 256;
      int r = idx >> 4, cc = (idx & 15) * 4;
      const float* Wrow = (r < 32) ? (Wq + (size_t)r * 512) : (Wk + (size_t)(r - 32) * 512);
      *(float4*)&ws[r][cc] = *(const float4*)&Wrow[c0 + cc];
    }
    __syncthreads();
    for (int c = 0; c < 64; c += 4) {
      float4 xa0 = *(const float4*)&xs[c + 0][n0];
      float4 xa1 = *(const float4*)&xs[c + 1][n0];
      float4 xa2 = *(const float4*)&xs[c + 2][n0];
      float4 xa3 = *(const float4*)&xs[c + 3][n0];
#pragma unroll
      for (int i = 0; i < 4; ++i) {
        float4 wa = *(const float4*)&ws[r0 + i][c];
        acc[i][0] += wa.x * xa0.x + wa.y * xa1.x + wa.z * xa2.x + wa.w * xa3.x;
        acc[i][1] += wa.x * xa0.y + wa.y * xa1.y + wa.z * xa2.y + wa.w * xa3.y;
        acc[i][2] += wa.x * xa0.z + wa.y * xa1.z + wa.z * xa2.z + wa.w * xa3.z;
        acc[i][3] += wa.x * xa0.w + wa.y * xa1.w + wa.z * xa2.w + wa.w * xa3.w;
      }
    }
    __syncthreads();
  }

  const float LOG2E = 1.4426950408889634f;
#pragma unroll
  for (int i = 0; i < 4; ++i) {
    int r = r0 + i;
#pragma unroll
    for (int j = 0; j < 4; ++j) {
      int n = nb + n0 + j;
      if (r < 32) {
        Qb[((size_t)(b * 4096 + n)) * 32 + r] = f2bf((acc[i][j] + bq[r]) * LOG2E);
      } else {
        Kb[((size_t)(b * 4096 + n)) * 32 + (r - 32)] = f2bf(acc[i][j] + bk[r - 32]);
      }
    }
  }
}

// ---------------------------------------------------------------------------
// V projection: V2 swizzled-tile layout for attn LDS staging.
//   V2 u16 index: b*2097152 + (n>>6)*32768 + c*64 + (((kk*2)^((c&7)<<4))>>1),
//   kk = n&63. grid = (n-tiles=64, b=8); block covers ALL 512 o (og loop).
// ---------------------------------------------------------------------------
__global__ __launch_bounds__(256) void v_proj(
    const float* __restrict__ x, const u16* __restrict__ Wvb,
    const float* __restrict__ bv, u16* __restrict__ V2) {
  const int b = blockIdx.y, nb = blockIdx.x * 64;
  const int t = threadIdx.x, w = t >> 6, lane = t & 63, g = lane >> 4, l15 = lane & 15;
  const int wo = (w >> 1) * 32, wn = (w & 1) * 32;
  __shared__ __align__(16) u16 xT[64][64];  // row = n (128B rows), swizzled

  f32x4 zero4 = {0.f, 0.f, 0.f, 0.f};
  f32x4 acc[8][2][2];
#pragma unroll
  for (int og = 0; og < 8; ++og)
#pragma unroll
    for (int ot = 0; ot < 2; ++ot)
#pragma unroll
      for (int nt = 0; nt < 2; ++nt) acc[og][ot][nt] = zero4;

  const int cq4 = (t >> 4) * 4, n4 = (t & 15) * 4;

  for (int c0 = 0; c0 < 512; c0 += 64) {
    float4 q0 = *(const float4*)&x[((size_t)(b * 512 + c0 + cq4 + 0)) * 4096 + nb + n4];
    float4 q1 = *(const float4*)&x[((size_t)(b * 512 + c0 + cq4 + 1)) * 4096 + nb + n4];
    float4 q2 = *(const float4*)&x[((size_t)(b * 512 + c0 + cq4 + 2)) * 4096 + nb + n4];
    float4 q3 = *(const float4*)&x[((size_t)(b * 512 + c0 + cq4 + 3)) * 4096 + nb + n4];
    float rr[4][4];
    rr[0][0] = q0.x; rr[0][1] = q0.y; rr[0][2] = q0.z; rr[0][3] = q0.w;
    rr[1][0] = q1.x; rr[1][1] = q1.y; rr[1][2] = q1.z; rr[1][3] = q1.w;
    rr[2][0] = q2.x; rr[2][1] = q2.y; rr[2][2] = q2.z; rr[2][3] = q2.w;
    rr[3][0] = q3.x; rr[3][1] = q3.y; rr[3][2] = q3.z; rr[3][3] = q3.w;
#pragma unroll
    for (int k = 0; k < 4; ++k) {
      int row = n4 + k;
      uint2 pk;
      pk.x = pack2(f2bf(rr[0][k]), f2bf(rr[1][k]));
      pk.y = pack2(f2bf(rr[2][k]), f2bf(rr[3][k]));
      int byte = row * 128 + ((cq4 * 2) ^ ((row & 7) << 4));
      *(uint2*)((char*)&xT[0][0] + byte) = pk;
    }
    __syncthreads();

    short8 bb[2][2];
#pragma unroll
    for (int nt = 0; nt < 2; ++nt)
#pragma unroll
      for (int ks = 0; ks < 2; ++ks) {
        int row = wn + nt * 16 + l15;
        int byte = row * 128 + (((ks * 64) + (g * 16)) ^ ((row & 7) << 4));
        bb[nt][ks] = *(const short8*)((const char*)&xT[0][0] + byte);
      }
#pragma unroll
    for (int og = 0; og < 8; ++og) {
      short8 af[2][2];
#pragma unroll
      for (int ot = 0; ot < 2; ++ot)
#pragma unroll
        for (int ks = 0; ks < 2; ++ks)
          af[ot][ks] = *(const short8*)&Wvb[(size_t)(og * 64 + wo + ot * 16 + l15) * 512 + c0 + ks * 32 + g * 8];
#pragma unroll
      for (int ks = 0; ks < 2; ++ks)
#pragma unroll
        for (int ot = 0; ot < 2; ++ot)
#pragma unroll
          for (int nt = 0; nt < 2; ++nt)
            acc[og][ot][nt] = MFMA16(af[ot][ks], bb[nt][ks], acc[og][ot][nt]);
    }
    __syncthreads();
  }

  const size_t tbase = (size_t)b * 2097152 + (size_t)(nb >> 6) * 32768;
#pragma unroll
  for (int og = 0; og < 8; ++og)
#pragma unroll
    for (int ot = 0; ot < 2; ++ot)
#pragma unroll
      for (int nt = 0; nt < 2; ++nt)
#pragma unroll
        for (int r = 0; r < 4; ++r) {
          int o = og * 64 + wo + ot * 16 + g * 4 + r;
          int kk = wn + nt * 16 + l15;
          int swz = ((kk * 2) ^ ((o & 7) << 4)) >> 1;
          V2[tbase + o * 64 + swz] = f2bf(acc[og][ot][nt][r] + bv[o]);
        }
}

// ---------------------------------------------------------------------------
// Flash attention v4b: as v4 (wave pair qg/chh, shared Plds, double-buffered
// Vlds) but V staging via global_load_lds DMA — zero staging VGPRs.
// V2 is pre-swizzled in global so the LDS image is a LINEAR copy (wave-
// uniform dest + lane*16), exactly matching the DMA semantics.
// ---------------------------------------------------------------------------
__global__ __launch_bounds__(512, 1) void attn4(
    const u16* __restrict__ Qb, const u16* __restrict__ Kb,
    const u16* __restrict__ V2, u16* __restrict__ AOb) {
  const int bid = blockIdx.x;
  const int b = bid & 7;                 // XCD-pinned batch
  const int qblk = (bid >> 3) * 128;
  const int t = threadIdx.x;
  const int w = t >> 6, lane = t & 63, g = lane >> 4, l15 = lane & 15;
  const int qg = w & 3, chh = w >> 2;    // SIMD i hosts (qg=i,chh=0)+(qg=i,chh=1)
  const int qbase = qblk + qg * 32;
  const int chb = chh * 256;

  __shared__ __align__(16) u16 Vlds[2][32768];   // [buf][512ch][64k] swizzled
  __shared__ __align__(16) u16 Plds[4][32][88];  // per q-group, shared
  __shared__ float lsum[4][32];

  f32x4 zero4 = {0.f, 0.f, 0.f, 0.f};

  short8 qf[2];
  if (chh == 0) {
#pragma unroll
    for (int qt = 0; qt < 2; ++qt)
      qf[qt] = *(const short8*)&Qb[((size_t)(b * 4096 + qbase + qt * 16 + l15)) * 32 + g * 8];
  }

  f32x4 acc[2][16];
#pragma unroll
  for (int qt = 0; qt < 2; ++qt)
#pragma unroll
    for (int ct = 0; ct < 16; ++ct) acc[qt][ct] = zero4;
  float l_[2][4] = {{0.f, 0.f, 0.f, 0.f}, {0.f, 0.f, 0.f, 0.f}};

  const char* VBb = (const char*)(V2 + (size_t)b * 2097152);  // byte base
  const size_t kb0 = (size_t)b * 4096;

  // prologue: DMA V tile 0 into buf 0 (wave w copies its 8KB slice)
  {
    const char* gsrc = VBb + w * 8192 + lane * 16;
    char* ldst = (char*)&Vlds[0][0] + w * 8192;
#pragma unroll
    for (int j = 0; j < 8; ++j) gld_lds16(gsrc + j * 1024, ldst + j * 1024);
  }
  __syncthreads();   // drains vmcnt (compiler waitcnt before barrier)

  for (int kv = 0; kv < 4096; kv += 64) {
    const int buf = (kv >> 6) & 1;
    const bool more = (kv + 64) < 4096;

    // 1) issue next-tile DMA (no registers, latency hides under S+softmax)
    if (more) {
      const char* gsrc = VBb + (size_t)((kv >> 6) + 1) * 65536 + w * 8192 + lane * 16;
      char* ldst = (char*)&Vlds[buf ^ 1][0] + w * 8192;
#pragma unroll
      for (int j = 0; j < 8; ++j) gld_lds16(gsrc + j * 1024, ldst + j * 1024);
    }

    // 2) S (chh0 only): 32q x 64 keys
    if (chh == 0) {
      f32x4 s[2][4];
#pragma unroll
      for (int ks = 0; ks < 4; ++ks) {
        short8 kf = *(const short8*)&Kb[(kb0 + kv + ks * 16 + l15) * 32 + g * 8];
        s[0][ks] = MFMA16(qf[0], kf, zero4);
        s[1][ks] = MFMA16(qf[1], kf, zero4);
      }
      // 3) softmax: p = 2^s, row sums, P -> shared Plds[qg]
#pragma unroll
      for (int qt = 0; qt < 2; ++qt)
#pragma unroll
        for (int r = 0; r < 4; ++r) {
          float rs = 0.f;
#pragma unroll
          for (int ks = 0; ks < 4; ++ks) {
            float p = exp2f(s[qt][ks][r]);
            rs += p;
            Plds[qg][qt * 16 + g * 4 + r][ks * 16 + l15] = f2bf(p);
          }
          rs += __shfl_xor(rs, 1);
          rs += __shfl_xor(rs, 2);
          rs += __shfl_xor(rs, 4);
          rs += __shfl_xor(rs, 8);
          l_[qt][r] += rs;
        }
    }
    __syncthreads();   // P(t) visible; V(t+1) DMA drained

    // 4) PV: both ch-halves, V from Vlds[buf], P from Plds[qg]
    short8 pf[2][2];
#pragma unroll
    for (int qt = 0; qt < 2; ++qt)
#pragma unroll
      for (int k2 = 0; k2 < 2; ++k2)
        pf[qt][k2] = *(const short8*)&Plds[qg][qt * 16 + l15][k2 * 32 + g * 8];
#pragma unroll
    for (int ct = 0; ct < 16; ++ct) {
      int c = chb + ct * 16 + l15;
      int sw = (c & 7) << 4;
      const char* vrow = (const char*)&Vlds[buf][0] + c * 128;
      short8 vf0 = *(const short8*)(vrow + ((g * 16) ^ sw));
      short8 vf1 = *(const short8*)(vrow + ((64 + g * 16) ^ sw));
      acc[0][ct] = MFMA16(pf[0][0], vf0, acc[0][ct]);
      acc[0][ct] = MFMA16(pf[0][1], vf1, acc[0][ct]);
      acc[1][ct] = MFMA16(pf[1][0], vf0, acc[1][ct]);
      acc[1][ct] = MFMA16(pf[1][1], vf1, acc[1][ct]);
    }
    __syncthreads();   // PV reads done before next iter's P write / V DMA
  }

  // epilogue: share row sums, normalize, store AO [B][N][C]
  if (chh == 0 && l15 == 0) {
#pragma unroll
    for (int qt = 0; qt < 2; ++qt)
#pragma unroll
      for (int r = 0; r < 4; ++r)
        lsum[qg][qt * 16 + g * 4 + r] = l_[qt][r];
  }
  __syncthreads();

#pragma unroll
  for (int qt = 0; qt < 2; ++qt) {
    float inv[4];
#pragma unroll
    for (int r = 0; r < 4; ++r) inv[r] = 1.0f / lsum[qg][qt * 16 + g * 4 + r];
#pragma unroll
    for (int ct = 0; ct < 16; ++ct)
#pragma unroll
      for (int r = 0; r < 4; ++r) {
        int qrow = qbase + qt * 16 + g * 4 + r;
        int c = chb + ct * 16 + l15;
        AOb[((size_t)(b * 4096 + qrow)) * 512 + c] = f2bf(acc[qt][ct][r] * inv[r]);
      }
  }
}

// ---------------------------------------------------------------------------
// Output projection + residual: out = gamma*(Wo AO + bo) + x -> FP32 d_out
// grid = (n-tiles=64, b=8); block covers ALL 512 o (og loop), x read once.
// ---------------------------------------------------------------------------
__global__ __launch_bounds__(256) void wo_out(
    const u16* __restrict__ AOb, const u16* __restrict__ Wob,
    const float* __restrict__ bo, const float* __restrict__ gamma,
    const float* __restrict__ x, float* __restrict__ out) {
  const int b = blockIdx.y, nb = blockIdx.x * 64;
  const int t = threadIdx.x, w = t >> 6, lane = t & 63, g = lane >> 4, l15 = lane & 15;
  const int wo = (w >> 1) * 32, wn = (w & 1) * 32;

  f32x4 zero4 = {0.f, 0.f, 0.f, 0.f};
  f32x4 acc[8][2][2];
#pragma unroll
  for (int og = 0; og < 8; ++og)
#pragma unroll
    for (int ot = 0; ot < 2; ++ot)
#pragma unroll
      for (int nt = 0; nt < 2; ++nt) acc[og][ot][nt] = zero4;

  for (int c0 = 0; c0 < 512; c0 += 64) {
    short8 bb[2][2];
#pragma unroll
    for (int nt = 0; nt < 2; ++nt)
#pragma unroll
      for (int ks = 0; ks < 2; ++ks)
        bb[nt][ks] = *(const short8*)&AOb[((size_t)(b * 4096 + nb + wn + nt * 16 + l15)) * 512 + c0 + ks * 32 + g * 8];
#pragma unroll
    for (int og = 0; og < 8; ++og) {
      short8 af[2][2];
#pragma unroll
      for (int ot = 0; ot < 2; ++ot)
#pragma unroll
        for (int ks = 0; ks < 2; ++ks)
          af[ot][ks] = *(const short8*)&Wob[(size_t)(og * 64 + wo + ot * 16 + l15) * 512 + c0 + ks * 32 + g * 8];
#pragma unroll
      for (int ks = 0; ks < 2; ++ks)
#pragma unroll
        for (int ot = 0; ot < 2; ++ot)
#pragma unroll
          for (int nt = 0; nt < 2; ++nt)
            acc[og][ot][nt] = MFMA16(af[ot][ks], bb[nt][ks], acc[og][ot][nt]);
    }
  }

  float gm = gamma[0];
#pragma unroll
  for (int og = 0; og < 8; ++og)
#pragma unroll
    for (int ot = 0; ot < 2; ++ot)
#pragma unroll
      for (int nt = 0; nt < 2; ++nt)
#pragma unroll
        for (int r = 0; r < 4; ++r) {
          int o = og * 64 + wo + ot * 16 + g * 4 + r;
          int n = nb + wn + nt * 16 + l15;
          size_t idx = ((size_t)(b * 512 + o)) * 4096 + n;
          out[idx] = gm * (acc[og][ot][nt][r] + bo[o]) + x[idx];
        }
}

// ---------------------------------------------------------------------------
// Workspace map (38.8 MB):
//   AOb ws+0 (32MB) | Qb ws+32M (2MB) | Kb ws+34M (2MB) | Wvb, Wob (1MB)
//   V2 = d_out scratch (32MB inside 64MB fp32 d_out), consumed by attn4
//   before wo_out rewrites every d_out element.
// ---------------------------------------------------------------------------
extern "C" void kernel_launch(void* const* d_in, const int* in_sizes, int n_in,
                              void* d_out, int out_size, void* d_ws, size_t ws_size,
                              hipStream_t stream) {
  (void)in_sizes; (void)n_in; (void)out_size; (void)ws_size;
  const float* x     = (const float*)d_in[0];
  const float* Wq    = (const float*)d_in[1];
  const float* bq    = (const float*)d_in[2];
  const float* Wk    = (const float*)d_in[3];
  const float* bk    = (const float*)d_in[4];
  const float* Wv    = (const float*)d_in[5];
  const float* bv    = (const float*)d_in[6];
  const float* Wo    = (const float*)d_in[7];
  const float* bo    = (const float*)d_in[8];
  const float* gamma = (const float*)d_in[9];

  char* wsb = (char*)d_ws;
  u16* AOb = (u16*)(wsb + 0);
  u16* Qb  = (u16*)(wsb + (size_t)33554432);
  u16* Kb  = (u16*)(wsb + (size_t)35651584);
  u16* Wvb = (u16*)(wsb + (size_t)37748736);
  u16* Wob = (u16*)(wsb + (size_t)38273024);
  u16* V2  = (u16*)d_out;  // scratch inside fp32 d_out; rewritten by wo_out

  conv_w<<<256, 256, 0, stream>>>(Wv, Wvb, 65536);
  conv_w<<<256, 256, 0, stream>>>(Wo, Wob, 65536);
  qk_proj<<<dim3(64, 8), 256, 0, stream>>>(x, Wq, bq, Wk, bk, Qb, Kb);
  v_proj<<<dim3(64, 8), 256, 0, stream>>>(x, Wvb, bv, V2);
  attn4<<<256, 512, 0, stream>>>(Qb, Kb, V2, AOb);
  wo_out<<<dim3(64, 8), 256, 0, stream>>>(AOb, Wob, bo, gamma, x, (float*)d_out);
}